// Round 1
// baseline (10927.528 us; speedup 1.0000x reference)
//
#include <hip/hip_runtime.h>
#include <hip/hip_cooperative_groups.h>
#include <hip/hip_bf16.h>

namespace cg = cooperative_groups;

#define SEQ 128
#define BAT 64
#define VOC 10000
#define EMBD 512
#define HID 512
#define BH (BAT*HID)                  // 32768
// workspace layout (floats)
#define PRE0_OFF 0
#define H0_OFF   ((size_t)SEQ*BH)     // 4,194,304
#define H1_OFF   (H0_OFF + (size_t)(SEQ+1)*BH)
#define LOGITS_N ((size_t)SEQ*BAT*VOC) // 81,920,000
// total ws use: 12,648,448 floats = 50.6 MB

__global__ __launch_bounds__(256) void init_state_k(const float* __restrict__ hidden,
                                                    float* __restrict__ h0_0,
                                                    float* __restrict__ h1_0) {
    int i = blockIdx.x * 256 + threadIdx.x;
    if (i < BH) { h0_0[i] = hidden[i]; h1_0[i] = hidden[BH + i]; }
}

// C[M,N] = A'[M,K] @ Bm[N,K]^T (+bias0+bias1), A' rows gathered via tok if non-null.
// BM=BN=128, BK=32, 256 threads, 8x8 micro-tile. Grid: (M/128, ceil(N/128)).
__global__ __launch_bounds__(256) void gemm_nt_k(
    const float* __restrict__ A, const int* __restrict__ tok,
    const float* __restrict__ Bm,
    const float* __restrict__ bias0, const float* __restrict__ bias1,
    float* __restrict__ C, int N, int K, int ldc)
{
    __shared__ float As[32][132];   // k-major, padded
    __shared__ float Bs[32][132];
    __shared__ int toks[128];

    const int tid = threadIdx.x;
    const int r0 = blockIdx.x * 128;
    const int c0 = blockIdx.y * 128;

    if (tok != nullptr && tid < 128) toks[tid] = tok[r0 + tid];
    __syncthreads();

    const int tn = tid & 15;        // -> contiguous C columns within a wave
    const int tm = tid >> 4;
    const int m0 = tm * 8, n0 = tn * 8;

    float acc[8][8];
#pragma unroll
    for (int i = 0; i < 8; ++i)
#pragma unroll
        for (int j = 0; j < 8; ++j) acc[i][j] = 0.f;

    for (int k0 = 0; k0 < K; k0 += 32) {
#pragma unroll
        for (int p = 0; p < 4; ++p) {
            int idx = p * 256 + tid;       // 0..1023
            int row = idx >> 3;            // 0..127
            int kq  = (idx & 7) << 2;      // 0,4,..,28
            size_t arow = tok ? (size_t)toks[row] : (size_t)(r0 + row);
            float4 a = *(const float4*)(A + arow * (size_t)K + k0 + kq);
            As[kq+0][row] = a.x; As[kq+1][row] = a.y;
            As[kq+2][row] = a.z; As[kq+3][row] = a.w;
            int gc = c0 + row;
            float4 b = make_float4(0.f, 0.f, 0.f, 0.f);
            if (gc < N) b = *(const float4*)(Bm + (size_t)gc * K + k0 + kq);
            Bs[kq+0][row] = b.x; Bs[kq+1][row] = b.y;
            Bs[kq+2][row] = b.z; Bs[kq+3][row] = b.w;
        }
        __syncthreads();
#pragma unroll 8
        for (int k = 0; k < 32; ++k) {
            float4 a0 = *(const float4*)&As[k][m0];
            float4 a1 = *(const float4*)&As[k][m0 + 4];
            float4 b0 = *(const float4*)&Bs[k][n0];
            float4 b1 = *(const float4*)&Bs[k][n0 + 4];
            float am[8] = {a0.x,a0.y,a0.z,a0.w,a1.x,a1.y,a1.z,a1.w};
            float bn[8] = {b0.x,b0.y,b0.z,b0.w,b1.x,b1.y,b1.z,b1.w};
#pragma unroll
            for (int i = 0; i < 8; ++i)
#pragma unroll
                for (int j = 0; j < 8; ++j) acc[i][j] += am[i] * bn[j];
        }
        __syncthreads();
    }

    float bj[8];
#pragma unroll
    for (int j = 0; j < 8; ++j) {
        int c = c0 + n0 + j;
        float v = 0.f;
        if (c < N) {
            if (bias0) v += bias0[c];
            if (bias1) v += bias1[c];
        }
        bj[j] = v;
    }
    const bool full = (c0 + 128 <= N);
#pragma unroll
    for (int i = 0; i < 8; ++i) {
        size_t r = (size_t)(r0 + m0 + i);
        float* crow = C + r * (size_t)ldc + c0 + n0;
        if (full) {
            float4 v0 = make_float4(acc[i][0]+bj[0], acc[i][1]+bj[1],
                                    acc[i][2]+bj[2], acc[i][3]+bj[3]);
            float4 v1 = make_float4(acc[i][4]+bj[4], acc[i][5]+bj[5],
                                    acc[i][6]+bj[6], acc[i][7]+bj[7]);
            *(float4*)(crow)     = v0;
            *(float4*)(crow + 4) = v1;
        } else {
#pragma unroll
            for (int j = 0; j < 8; ++j) {
                int c = c0 + n0 + j;
                if (c < N) crow[j] = acc[i][j] + bj[j];
            }
        }
    }
}

__device__ __forceinline__ float dot_span(const float* __restrict__ x,
                                          const float* __restrict__ w, int n) {
    float4 a = make_float4(0.f, 0.f, 0.f, 0.f);
#pragma unroll 4
    for (int k = 0; k < n; k += 4) {
        float4 xv = *(const float4*)(x + k);
        float4 wv = *(const float4*)(w + k);
        a.x += xv.x * wv.x; a.y += xv.y * wv.y;
        a.z += xv.z * wv.z; a.w += xv.w * wv.w;
    }
    return (a.x + a.y) + (a.z + a.w);
}

// Cooperative recurrence. 512 blocks x 256 threads.
// blocks 0..255: layer-1 step s (s<128); blocks 256..511: layer-2 step s-1 (s>=1).
// Each block: 16 b x 8 j outputs, 2-way K split reduced via shfl_xor(32).
__global__ __launch_bounds__(256) void recurrence_k(
    const float* __restrict__ pre0,
    const float* __restrict__ W_hh0,
    const float* __restrict__ W_in, const float* __restrict__ b_in,
    const float* __restrict__ W_hh, const float* __restrict__ b_hh,
    float* __restrict__ h0_all, float* __restrict__ h1_all,
    float* __restrict__ out_hidden)
{
    cg::grid_group grid = cg::this_grid();
    const int blk = blockIdx.x;
    const int tid = threadIdx.x;
    const int task = blk >> 8;         // 0 or 1
    const int bt = blk & 255;
    const int b_blk = bt >> 6;         // 0..3
    const int j_blk = bt & 63;         // 0..63
    const int b = b_blk * 16 + (tid & 15);
    const int j_low  = (tid >> 4) & 1;
    const int kh     = (tid >> 5) & 1; // lane bit 5 -> shfl_xor(32) partner
    const int j_high = tid >> 6;       // 0..3
    const int j = j_blk * 8 + j_high * 2 + j_low;

    for (int s = 0; s <= SEQ; ++s) {
        if (task == 0) {
            if (s < SEQ) {
                const float* x = h0_all + (size_t)s * BH + b * HID + kh * 256;
                const float* w = W_hh0 + j * HID + kh * 256;
                float p = dot_span(x, w, 256);
                p += __shfl_xor(p, 32);
                if (kh == 0) {
                    float v = tanhf(p + pre0[(size_t)s * BH + b * HID + j]);
                    h0_all[(size_t)(s + 1) * BH + b * HID + j] = v;
                }
            }
        } else {
            if (s >= 1) {
                const float* x; const float* w;
                if (kh == 0) { x = h0_all + (size_t)s * BH + b * HID;       w = W_in + j * HID; }
                else         { x = h1_all + (size_t)(s - 1) * BH + b * HID; w = W_hh + j * HID; }
                float p = dot_span(x, w, HID);
                p += __shfl_xor(p, 32);
                if (kh == 0) {
                    float v = tanhf(p + b_in[j] + b_hh[j]);
                    h1_all[(size_t)s * BH + b * HID + j] = v;
                }
            }
        }
        grid.sync();
    }

    // final hidden: d_out tail = [h0[127], h1[127]]
    int g = blk * 256 + tid;
    if (g < BH)            out_hidden[g] = h0_all[(size_t)SEQ * BH + g];
    else if (g < 2 * BH)   out_hidden[g] = h1_all[(size_t)SEQ * BH + (g - BH)];
}

extern "C" void kernel_launch(void* const* d_in, const int* in_sizes, int n_in,
                              void* d_out, int out_size, void* d_ws, size_t ws_size,
                              hipStream_t stream) {
    const int*   inputs = (const int*)d_in[0];
    const float* hidden = (const float*)d_in[1];
    const float* emb    = (const float*)d_in[2];
    const float* W_ih0  = (const float*)d_in[3];
    const float* b_ih0  = (const float*)d_in[4];
    const float* W_hh0  = (const float*)d_in[5];
    const float* b_hh0  = (const float*)d_in[6];
    const float* W_in   = (const float*)d_in[7];
    const float* b_in   = (const float*)d_in[8];
    const float* W_hh   = (const float*)d_in[9];
    const float* b_hh   = (const float*)d_in[10];
    const float* Wy     = (const float*)d_in[11];
    const float* by     = (const float*)d_in[12];
    float* out = (float*)d_out;

    float* ws     = (float*)d_ws;
    float* pre0   = ws + PRE0_OFF;
    float* h0_all = ws + H0_OFF;
    float* h1_all = ws + H1_OFF;
    float* out_hidden = out + LOGITS_N;

    // 1) initial hidden state -> slot 0
    init_state_k<<<dim3((BH + 255) / 256), dim3(256), 0, stream>>>(hidden, h0_all, h1_all);

    // 2) pre0 = emb[tok] @ W_ih0^T + b_ih0 + b_hh0   (M=8192, N=512, K=512)
    gemm_nt_k<<<dim3(64, 4), dim3(256), 0, stream>>>(
        emb, inputs, W_ih0, b_ih0, b_hh0, pre0, HID, EMBD, HID);

    // 3) recurrence (cooperative, 129 grid syncs, pipelined layers)
    const float* pre0_c = pre0;
    void* kargs[] = { (void*)&pre0_c, (void*)&W_hh0, (void*)&W_in, (void*)&b_in,
                      (void*)&W_hh, (void*)&b_hh, (void*)&h0_all, (void*)&h1_all,
                      (void*)&out_hidden };
    hipLaunchCooperativeKernel((const void*)recurrence_k, dim3(512), dim3(256),
                               kargs, 0, stream);

    // 4) logits = h1_all[1..128] @ Wy^T + by   (M=8192, N=10000, K=512)
    gemm_nt_k<<<dim3(64, 79), dim3(256), 0, stream>>>(
        h1_all + BH, nullptr, Wy, nullptr, by, out, VOC, HID, VOC);
}

// Round 2
// 6410.700 us; speedup vs baseline: 1.7046x; 1.7046x over previous
//
#include <hip/hip_runtime.h>
#include <hip/hip_bf16.h>

#define SEQ 128
#define BAT 64
#define VOC 10000
#define EMBD 512
#define HID 512
#define BH (BAT*HID)                  // 32768
// workspace layout (floats)
#define PRE0_OFF 0
#define H0_OFF   ((size_t)SEQ*BH)     // 4,194,304
#define H1_OFF   (H0_OFF + (size_t)(SEQ+1)*BH)
#define CTR_OFF  (H1_OFF + (size_t)(SEQ+1)*BH)   // barrier counter (as float slot)
#define LOGITS_N ((size_t)SEQ*BAT*VOC) // 81,920,000
// total ws use: ~12.65M floats = 50.6 MB

__global__ __launch_bounds__(256) void init_state_k(const float* __restrict__ hidden,
                                                    float* __restrict__ h0_0,
                                                    float* __restrict__ h1_0,
                                                    unsigned* __restrict__ ctr) {
    int i = blockIdx.x * 256 + threadIdx.x;
    if (i == 0) *ctr = 0u;
    if (i < BH) { h0_0[i] = hidden[i]; h1_0[i] = hidden[BH + i]; }
}

// C[M,N] = A'[M,K] @ Bm[N,K]^T (+bias0+bias1), A' rows gathered via tok if non-null.
// BM=BN=128, BK=32, 256 threads, 8x8 micro-tile. Grid: (M/128, ceil(N/128)).
__global__ __launch_bounds__(256) void gemm_nt_k(
    const float* __restrict__ A, const int* __restrict__ tok,
    const float* __restrict__ Bm,
    const float* __restrict__ bias0, const float* __restrict__ bias1,
    float* __restrict__ C, int N, int K, int ldc)
{
    __shared__ float As[32][132];   // k-major, padded
    __shared__ float Bs[32][132];
    __shared__ int toks[128];

    const int tid = threadIdx.x;
    const int r0 = blockIdx.x * 128;
    const int c0 = blockIdx.y * 128;

    if (tok != nullptr && tid < 128) toks[tid] = tok[r0 + tid];
    __syncthreads();

    const int tn = tid & 15;        // -> contiguous C columns within a wave
    const int tm = tid >> 4;
    const int m0 = tm * 8, n0 = tn * 8;

    float acc[8][8];
#pragma unroll
    for (int i = 0; i < 8; ++i)
#pragma unroll
        for (int j = 0; j < 8; ++j) acc[i][j] = 0.f;

    for (int k0 = 0; k0 < K; k0 += 32) {
#pragma unroll
        for (int p = 0; p < 4; ++p) {
            int idx = p * 256 + tid;       // 0..1023
            int row = idx >> 3;            // 0..127
            int kq  = (idx & 7) << 2;      // 0,4,..,28
            size_t arow = tok ? (size_t)toks[row] : (size_t)(r0 + row);
            float4 a = *(const float4*)(A + arow * (size_t)K + k0 + kq);
            As[kq+0][row] = a.x; As[kq+1][row] = a.y;
            As[kq+2][row] = a.z; As[kq+3][row] = a.w;
            int gc = c0 + row;
            float4 b = make_float4(0.f, 0.f, 0.f, 0.f);
            if (gc < N) b = *(const float4*)(Bm + (size_t)gc * K + k0 + kq);
            Bs[kq+0][row] = b.x; Bs[kq+1][row] = b.y;
            Bs[kq+2][row] = b.z; Bs[kq+3][row] = b.w;
        }
        __syncthreads();
#pragma unroll 8
        for (int k = 0; k < 32; ++k) {
            float4 a0 = *(const float4*)&As[k][m0];
            float4 a1 = *(const float4*)&As[k][m0 + 4];
            float4 b0 = *(const float4*)&Bs[k][n0];
            float4 b1 = *(const float4*)&Bs[k][n0 + 4];
            float am[8] = {a0.x,a0.y,a0.z,a0.w,a1.x,a1.y,a1.z,a1.w};
            float bn[8] = {b0.x,b0.y,b0.z,b0.w,b1.x,b1.y,b1.z,b1.w};
#pragma unroll
            for (int i = 0; i < 8; ++i)
#pragma unroll
                for (int j = 0; j < 8; ++j) acc[i][j] += am[i] * bn[j];
        }
        __syncthreads();
    }

    float bj[8];
#pragma unroll
    for (int j = 0; j < 8; ++j) {
        int c = c0 + n0 + j;
        float v = 0.f;
        if (c < N) {
            if (bias0) v += bias0[c];
            if (bias1) v += bias1[c];
        }
        bj[j] = v;
    }
    const bool full = (c0 + 128 <= N);
#pragma unroll
    for (int i = 0; i < 8; ++i) {
        size_t r = (size_t)(r0 + m0 + i);
        float* crow = C + r * (size_t)ldc + c0 + n0;
        if (full) {
            float4 v0 = make_float4(acc[i][0]+bj[0], acc[i][1]+bj[1],
                                    acc[i][2]+bj[2], acc[i][3]+bj[3]);
            float4 v1 = make_float4(acc[i][4]+bj[4], acc[i][5]+bj[5],
                                    acc[i][6]+bj[6], acc[i][7]+bj[7]);
            *(float4*)(crow)     = v0;
            *(float4*)(crow + 4) = v1;
        } else {
#pragma unroll
            for (int j = 0; j < 8; ++j) {
                int c = c0 + n0 + j;
                if (c < N) crow[j] = acc[i][j] + bj[j];
            }
        }
    }
}

__device__ __forceinline__ float dot_span(const float* __restrict__ x,
                                          const float* __restrict__ w, int n) {
    float4 a = make_float4(0.f, 0.f, 0.f, 0.f);
#pragma unroll 4
    for (int k = 0; k < n; k += 4) {
        float4 xv = *(const float4*)(x + k);
        float4 wv = *(const float4*)(w + k);
        a.x += xv.x * wv.x; a.y += xv.y * wv.y;
        a.z += xv.z * wv.z; a.w += xv.w * wv.w;
    }
    return (a.x + a.y) + (a.z + a.w);
}

// agent-scope (cross-XCD coherent, sc1) store: write-through to the coherence
// point so other XCDs' plain loads (which cannot hit a stale line -- each h
// slot's lines are never touched by any CU before the barrier that publishes
// them) observe the value. No cache-maintenance instructions anywhere.
__device__ __forceinline__ void st_agent(float* p, float v) {
    __hip_atomic_store(p, v, __ATOMIC_RELAXED, __HIP_MEMORY_SCOPE_AGENT);
}

// Monotonic centralized barrier: relaxed fetch_add + relaxed poll (no acquire/
// release -> no L2 writeback/invalidate, unlike cg::grid_group::sync()).
// Producer visibility is guaranteed by the explicit vmcnt(0) drain (all sc1
// stores retired at the coherence point) before arrival.
__device__ __forceinline__ void barrier_sync(unsigned* ctr, unsigned target) {
    __syncthreads();
    if (threadIdx.x == 0) {
        asm volatile("s_waitcnt vmcnt(0)" ::: "memory");
        unsigned prev = __hip_atomic_fetch_add(ctr, 1u, __ATOMIC_RELAXED,
                                               __HIP_MEMORY_SCOPE_AGENT);
        if (prev + 1u < target) {
            while (__hip_atomic_load(ctr, __ATOMIC_RELAXED,
                                     __HIP_MEMORY_SCOPE_AGENT) < target) {
                __builtin_amdgcn_s_sleep(1);
            }
        }
    }
    __syncthreads();
}

// Recurrence: 512 blocks x 256 threads (cooperative launch for co-residency
// only; grid.sync() NOT used).
// blocks 0..255: layer-1 step s (s<128); blocks 256..511: layer-2 step s-1.
// Each block: 16 b x 8 j outputs, 2-way K split reduced via shfl_xor(32).
__global__ __launch_bounds__(256) void recurrence_k(
    const float* __restrict__ pre0,
    const float* __restrict__ W_hh0,
    const float* __restrict__ W_in, const float* __restrict__ b_in,
    const float* __restrict__ W_hh, const float* __restrict__ b_hh,
    float* __restrict__ h0_all, float* __restrict__ h1_all,
    float* __restrict__ out_hidden, unsigned* __restrict__ ctr)
{
    const int blk = blockIdx.x;
    const int tid = threadIdx.x;
    const int task = blk >> 8;         // 0 or 1
    const int bt = blk & 255;
    const int b_blk = bt >> 6;         // 0..3
    const int j_blk = bt & 63;         // 0..63
    const int b = b_blk * 16 + (tid & 15);
    const int j_low  = (tid >> 4) & 1;
    const int kh     = (tid >> 5) & 1; // lane bit 5 -> shfl_xor(32) partner
    const int j_high = tid >> 6;       // 0..3
    const int j = j_blk * 8 + j_high * 2 + j_low;

    for (int s = 0; s <= SEQ; ++s) {
        if (task == 0) {
            if (s < SEQ) {
                const float* x = h0_all + (size_t)s * BH + b * HID + kh * 256;
                const float* w = W_hh0 + j * HID + kh * 256;
                float p = dot_span(x, w, 256);
                p += __shfl_xor(p, 32);
                if (kh == 0) {
                    float v = tanhf(p + pre0[(size_t)s * BH + b * HID + j]);
                    st_agent(&h0_all[(size_t)(s + 1) * BH + b * HID + j], v);
                }
            }
        } else {
            if (s >= 1) {
                const float* x; const float* w;
                if (kh == 0) { x = h0_all + (size_t)s * BH + b * HID;       w = W_in + j * HID; }
                else         { x = h1_all + (size_t)(s - 1) * BH + b * HID; w = W_hh + j * HID; }
                float p = dot_span(x, w, HID);
                p += __shfl_xor(p, 32);
                if (kh == 0) {
                    float v = tanhf(p + b_in[j] + b_hh[j]);
                    st_agent(&h1_all[(size_t)s * BH + b * HID + j], v);
                }
            }
        }
        barrier_sync(ctr, 512u * (unsigned)(s + 1));
    }

    // final hidden: d_out tail = [h0[127], h1[127]]
    int g = blk * 256 + tid;
    if (g < BH)            out_hidden[g] = h0_all[(size_t)SEQ * BH + g];
    else if (g < 2 * BH)   out_hidden[g] = h1_all[(size_t)SEQ * BH + (g - BH)];
}

extern "C" void kernel_launch(void* const* d_in, const int* in_sizes, int n_in,
                              void* d_out, int out_size, void* d_ws, size_t ws_size,
                              hipStream_t stream) {
    const int*   inputs = (const int*)d_in[0];
    const float* hidden = (const float*)d_in[1];
    const float* emb    = (const float*)d_in[2];
    const float* W_ih0  = (const float*)d_in[3];
    const float* b_ih0  = (const float*)d_in[4];
    const float* W_hh0  = (const float*)d_in[5];
    const float* b_hh0  = (const float*)d_in[6];
    const float* W_in   = (const float*)d_in[7];
    const float* b_in   = (const float*)d_in[8];
    const float* W_hh   = (const float*)d_in[9];
    const float* b_hh   = (const float*)d_in[10];
    const float* Wy     = (const float*)d_in[11];
    const float* by     = (const float*)d_in[12];
    float* out = (float*)d_out;

    float* ws     = (float*)d_ws;
    float* pre0   = ws + PRE0_OFF;
    float* h0_all = ws + H0_OFF;
    float* h1_all = ws + H1_OFF;
    unsigned* ctr = (unsigned*)(ws + CTR_OFF);
    float* out_hidden = out + LOGITS_N;

    // 1) initial hidden state -> slot 0; zero barrier counter
    init_state_k<<<dim3((BH + 255) / 256), dim3(256), 0, stream>>>(hidden, h0_all, h1_all, ctr);

    // 2) pre0 = emb[tok] @ W_ih0^T + b_ih0 + b_hh0   (M=8192, N=512, K=512)
    gemm_nt_k<<<dim3(64, 4), dim3(256), 0, stream>>>(
        emb, inputs, W_ih0, b_ih0, b_hh0, pre0, HID, EMBD, HID);

    // 3) recurrence (cooperative launch for co-residency; custom barrier)
    const float* pre0_c = pre0;
    void* kargs[] = { (void*)&pre0_c, (void*)&W_hh0, (void*)&W_in, (void*)&b_in,
                      (void*)&W_hh, (void*)&b_hh, (void*)&h0_all, (void*)&h1_all,
                      (void*)&out_hidden, (void*)&ctr };
    hipLaunchCooperativeKernel((const void*)recurrence_k, dim3(512), dim3(256),
                               kargs, 0, stream);

    // 4) logits = h1_all[1..128] @ Wy^T + by   (M=8192, N=10000, K=512)
    gemm_nt_k<<<dim3(64, 79), dim3(256), 0, stream>>>(
        h1_all + BH, nullptr, Wy, nullptr, by, out, VOC, HID, VOC);
}

// Round 4
// 3095.255 us; speedup vs baseline: 3.5304x; 2.0711x over previous
//
#include <hip/hip_runtime.h>
#include <hip/hip_bf16.h>

#define SEQ 128
#define BAT 64
#define VOC 10000
#define EMBD 512
#define HID 512
#define BH (BAT*HID)                  // 32768
// workspace layout (floats)
#define PRE0_OFF 0
#define H0_OFF   ((size_t)SEQ*BH)                 // pre0: 128*BH
#define H1_OFF   (H0_OFF + (size_t)(SEQ+1)*BH)
#define FLAGS_OFF (H1_OFF + (size_t)(SEQ+1)*BH)   // 512 uint flags
#define LOGITS_N ((size_t)SEQ*BAT*VOC)            // 81,920,000 (in d_out)

#define XSW(b) (((b)&15)<<2)          // LDS column XOR-swizzle per row

__global__ __launch_bounds__(256) void init_state_k(const float* __restrict__ hidden,
                                                    float* __restrict__ h0_0,
                                                    float* __restrict__ h1_0,
                                                    unsigned* __restrict__ flags) {
    int i = blockIdx.x * 256 + threadIdx.x;
    if (i < 512) flags[i] = 0u;    // flags0[256], flags1[256] <- "slot 0 ready"
    if (i < BH) { h0_0[i] = hidden[i]; h1_0[i] = hidden[BH + i]; }
}

// C[M,N] = A'[M,K] @ Bm[N,K]^T (+bias0+bias1), A' rows gathered via tok if non-null.
// BM=BN=128, BK=32, 256 threads, 8x8 micro-tile. Grid: (M/128, ceil(N/128)).
__global__ __launch_bounds__(256) void gemm_nt_k(
    const float* __restrict__ A, const int* __restrict__ tok,
    const float* __restrict__ Bm,
    const float* __restrict__ bias0, const float* __restrict__ bias1,
    float* __restrict__ C, int N, int K, int ldc)
{
    __shared__ float As[32][132];   // k-major, padded
    __shared__ float Bs[32][132];
    __shared__ int toks[128];

    const int tid = threadIdx.x;
    const int r0 = blockIdx.x * 128;
    const int c0 = blockIdx.y * 128;

    if (tok != nullptr && tid < 128) toks[tid] = tok[r0 + tid];
    __syncthreads();

    const int tn = tid & 15;        // -> contiguous C columns within a wave
    const int tm = tid >> 4;
    const int m0 = tm * 8, n0 = tn * 8;

    float acc[8][8];
#pragma unroll
    for (int i = 0; i < 8; ++i)
#pragma unroll
        for (int j = 0; j < 8; ++j) acc[i][j] = 0.f;

    for (int k0 = 0; k0 < K; k0 += 32) {
#pragma unroll
        for (int p = 0; p < 4; ++p) {
            int idx = p * 256 + tid;       // 0..1023
            int row = idx >> 3;            // 0..127
            int kq  = (idx & 7) << 2;      // 0,4,..,28
            size_t arow = tok ? (size_t)toks[row] : (size_t)(r0 + row);
            float4 a = *(const float4*)(A + arow * (size_t)K + k0 + kq);
            As[kq+0][row] = a.x; As[kq+1][row] = a.y;
            As[kq+2][row] = a.z; As[kq+3][row] = a.w;
            int gc = c0 + row;
            float4 b = make_float4(0.f, 0.f, 0.f, 0.f);
            if (gc < N) b = *(const float4*)(Bm + (size_t)gc * K + k0 + kq);
            Bs[kq+0][row] = b.x; Bs[kq+1][row] = b.y;
            Bs[kq+2][row] = b.z; Bs[kq+3][row] = b.w;
        }
        __syncthreads();
#pragma unroll 8
        for (int k = 0; k < 32; ++k) {
            float4 a0 = *(const float4*)&As[k][m0];
            float4 a1 = *(const float4*)&As[k][m0 + 4];
            float4 b0 = *(const float4*)&Bs[k][n0];
            float4 b1 = *(const float4*)&Bs[k][n0 + 4];
            float am[8] = {a0.x,a0.y,a0.z,a0.w,a1.x,a1.y,a1.z,a1.w};
            float bn[8] = {b0.x,b0.y,b0.z,b0.w,b1.x,b1.y,b1.z,b1.w};
#pragma unroll
            for (int i = 0; i < 8; ++i)
#pragma unroll
                for (int j = 0; j < 8; ++j) acc[i][j] += am[i] * bn[j];
        }
        __syncthreads();
    }

    float bj[8];
#pragma unroll
    for (int j = 0; j < 8; ++j) {
        int c = c0 + n0 + j;
        float v = 0.f;
        if (c < N) {
            if (bias0) v += bias0[c];
            if (bias1) v += bias1[c];
        }
        bj[j] = v;
    }
    const bool full = (c0 + 128 <= N);
#pragma unroll
    for (int i = 0; i < 8; ++i) {
        size_t r = (size_t)(r0 + m0 + i);
        float* crow = C + r * (size_t)ldc + c0 + n0;
        if (full) {
            float4 v0 = make_float4(acc[i][0]+bj[0], acc[i][1]+bj[1],
                                    acc[i][2]+bj[2], acc[i][3]+bj[3]);
            float4 v1 = make_float4(acc[i][4]+bj[4], acc[i][5]+bj[5],
                                    acc[i][6]+bj[6], acc[i][7]+bj[7]);
            *(float4*)(crow)     = v0;
            *(float4*)(crow + 4) = v1;
        } else {
#pragma unroll
            for (int j = 0; j < 8; ++j) {
                int c = c0 + n0 + j;
                if (c < N) crow[j] = acc[i][j] + bj[j];
            }
        }
    }
}

// agent-scope (cross-XCD) store: commits at the coherence point; tracked by vmcnt.
__device__ __forceinline__ void st_agent(float* p, float v) {
    __hip_atomic_store(p, v, __ATOMIC_RELAXED, __HIP_MEMORY_SCOPE_AGENT);
}
__device__ __forceinline__ void st_flag(unsigned* p, unsigned v) {
    __hip_atomic_store(p, v, __ATOMIC_RELAXED, __HIP_MEMORY_SCOPE_AGENT);
}

// wave0 polls fA[0..63] >= tA; wave1 polls fB[0..63] >= tB (if fB). Stale flag
// reads are conservative (monotonic counters) -> never unsafe, only slower.
__device__ __forceinline__ void wait_flags(const unsigned* __restrict__ fA, unsigned tA,
                                           const unsigned* __restrict__ fB, unsigned tB) {
    const int tid = threadIdx.x;
    if (tid < 64) {
        for (;;) {
            unsigned v = __hip_atomic_load(&fA[tid], __ATOMIC_RELAXED,
                                           __HIP_MEMORY_SCOPE_AGENT);
            if (__ballot(v < tA) == 0ull) break;
            __builtin_amdgcn_s_sleep(1);
        }
    } else if (fB != nullptr && tid < 128) {
        for (;;) {
            unsigned v = __hip_atomic_load(&fB[tid - 64], __ATOMIC_RELAXED,
                                           __HIP_MEMORY_SCOPE_AGENT);
            if (__ballot(v < tB) == 0ull) break;
            __builtin_amdgcn_s_sleep(1);
        }
    }
    __syncthreads();
}

// Stage one (or two) 32KB x-windows (16 rows x 512 floats, contiguous) into LDS
// with coherence-point-bypassing loads (sc0 sc1: skip L1+L2 -> no stale lines).
// LDS layout: row-major 512 stride, column XOR-swizzled by XSW(row) (2-way max
// bank aliasing on the dot reads = free).
__device__ __forceinline__ void stage2(const float* __restrict__ srcA,
                                       const float* __restrict__ srcB,
                                       float* __restrict__ lds) {
    float4 ra[8], rb[8];
    const float4* sA = (const float4*)srcA;
    const float4* sB = (const float4*)srcB;
#pragma unroll
    for (int i = 0; i < 8; ++i) {
        const float4* pa = sA + (threadIdx.x + (i << 8));
        asm volatile("global_load_dwordx4 %0, %1, off sc0 sc1"
                     : "=v"(ra[i]) : "v"(pa));
    }
    if (srcB != nullptr) {
#pragma unroll
        for (int i = 0; i < 8; ++i) {
            const float4* pb = sB + (threadIdx.x + (i << 8));
            asm volatile("global_load_dwordx4 %0, %1, off sc0 sc1"
                         : "=v"(rb[i]) : "v"(pb));
        }
    }
    asm volatile("s_waitcnt vmcnt(0)" ::: "memory");
    __builtin_amdgcn_sched_barrier(0);
#pragma unroll
    for (int i = 0; i < 8; ++i) {
        int q = threadIdx.x + (i << 8);
        int row = q >> 7;                  // 0..15
        int c4  = (q & 127) << 2;          // 0..508
        *(float4*)&lds[row * 512 + (c4 ^ XSW(row))] = ra[i];
    }
    if (srcB != nullptr) {
#pragma unroll
        for (int i = 0; i < 8; ++i) {
            int q = threadIdx.x + (i << 8);
            int row = q >> 7;
            int c4  = (q & 127) << 2;
            *(float4*)&lds[8192 + row * 512 + (c4 ^ XSW(row))] = rb[i];
        }
    }
}

// Dot of a swizzled LDS row segment against a (plain-cached) global weight row.
__device__ __forceinline__ float dot_lds(const float* __restrict__ xrow, int sw,
                                         const float* __restrict__ w, int n) {
    float4 a = make_float4(0.f, 0.f, 0.f, 0.f);
#pragma unroll 4
    for (int c = 0; c < n; c += 4) {
        float4 xv = *(const float4*)(xrow + (c ^ sw));
        float4 wv = *(const float4*)(w + c);
        a.x += xv.x * wv.x; a.y += xv.y * wv.y;
        a.z += xv.z * wv.z; a.w += xv.w * wv.w;
    }
    return (a.x + a.y) + (a.z + a.w);
}

// Dataflow recurrence: 512 blocks x 256 threads (coop launch = co-residency).
// blocks 0..255  (task0): layer-1, produce h0 slots t=1..128
// blocks 256..511(task1): layer-2, produce h1 slots t=1..128
// Per block: 16 b x 8 j outputs, 2-way K split reduced via shfl_xor(32).
__global__ __launch_bounds__(256) void recurrence_k(
    const float* __restrict__ pre0,
    const float* __restrict__ W_hh0,
    const float* __restrict__ W_in, const float* __restrict__ b_in,
    const float* __restrict__ W_hh, const float* __restrict__ b_hh,
    float* __restrict__ h0_all, float* __restrict__ h1_all,
    unsigned* __restrict__ flags)
{
    __shared__ float xs[2 * 8192];     // 64 KB -> exactly 2 blocks/CU

    const int blk = blockIdx.x;
    const int tid = threadIdx.x;
    const int task = blk >> 8;         // 0 or 1
    const int bt = blk & 255;
    const int b_blk = bt >> 6;         // 0..3
    const int b_local = tid & 15;
    const int b = (b_blk << 4) + b_local;
    const int j_low  = (tid >> 4) & 1;
    const int kh     = (tid >> 5) & 1; // lane bit 5 -> shfl_xor(32) partner
    const int j_high = tid >> 6;       // 0..3
    const int j = ((bt & 63) << 3) + (j_high << 1) + j_low;
    const int sw = XSW(b_local);

    unsigned* flags0 = flags;
    unsigned* flags1 = flags + 256;
    const unsigned* grp0 = flags0 + (b_blk << 6);   // 64 producer flags, layer 1
    const unsigned* grp1 = flags1 + (b_blk << 6);   // 64 producer flags, layer 2
    unsigned* myflag = (task == 0 ? flags0 : flags1) + bt;
    const size_t win = (size_t)(b_blk << 4) * HID;  // 16-row window offset

    if (task == 0) {
        const float* w = W_hh0 + (size_t)j * HID + kh * 256;
        for (unsigned t = 1; t <= SEQ; ++t) {
            wait_flags(grp0, t - 1, nullptr, 0);          // h0 slot t-1 ready
            stage2(h0_all + (size_t)(t - 1) * BH + win, nullptr, xs);
            __syncthreads();
            float p = dot_lds(xs + b_local * 512 + kh * 256, sw, w, 256);
            p += __shfl_xor(p, 32);
            if (kh == 0) {
                float v = tanhf(p + pre0[(size_t)(t - 1) * BH + b * HID + j]);
                st_agent(&h0_all[(size_t)t * BH + b * HID + j], v);
            }
            asm volatile("s_waitcnt vmcnt(0)" ::: "memory");  // data committed
            __syncthreads();
            if (tid == 0) st_flag(myflag, t);
        }
    } else {
        const float* w = (kh == 0) ? (W_in + (size_t)j * HID)
                                   : (W_hh + (size_t)j * HID);
        const float* xbase = xs + (kh ? 8192 : 0) + b_local * 512;
        for (unsigned t = 1; t <= SEQ; ++t) {
            wait_flags(grp0, t, grp1, t - 1);             // h0[t], h1[t-1] ready
            stage2(h0_all + (size_t)t * BH + win,
                   h1_all + (size_t)(t - 1) * BH + win, xs);
            __syncthreads();
            float p = dot_lds(xbase, sw, w, 512);
            p += __shfl_xor(p, 32);
            if (kh == 0) {
                float v = tanhf(p + b_in[j] + b_hh[j]);
                st_agent(&h1_all[(size_t)t * BH + b * HID + j], v);
            }
            asm volatile("s_waitcnt vmcnt(0)" ::: "memory");
            __syncthreads();
            if (tid == 0) st_flag(myflag, t);
        }
    }
}

__global__ __launch_bounds__(256) void copy_out_k(const float* __restrict__ h0_all,
                                                  const float* __restrict__ h1_all,
                                                  float* __restrict__ out_hidden) {
    int g = blockIdx.x * 256 + threadIdx.x;
    if (g < BH)            out_hidden[g] = h0_all[(size_t)SEQ * BH + g];
    else if (g < 2 * BH)   out_hidden[g] = h1_all[(size_t)SEQ * BH + (g - BH)];
}

extern "C" void kernel_launch(void* const* d_in, const int* in_sizes, int n_in,
                              void* d_out, int out_size, void* d_ws, size_t ws_size,
                              hipStream_t stream) {
    const int*   inputs = (const int*)d_in[0];
    const float* hidden = (const float*)d_in[1];
    const float* emb    = (const float*)d_in[2];
    const float* W_ih0  = (const float*)d_in[3];
    const float* b_ih0  = (const float*)d_in[4];
    const float* W_hh0  = (const float*)d_in[5];
    const float* b_hh0  = (const float*)d_in[6];
    const float* W_in   = (const float*)d_in[7];
    const float* b_in   = (const float*)d_in[8];
    const float* W_hh   = (const float*)d_in[9];
    const float* b_hh   = (const float*)d_in[10];
    const float* Wy     = (const float*)d_in[11];
    const float* by     = (const float*)d_in[12];
    float* out = (float*)d_out;

    float* ws     = (float*)d_ws;
    float* pre0   = ws + PRE0_OFF;
    float* h0_all = ws + H0_OFF;
    float* h1_all = ws + H1_OFF;
    unsigned* flags = (unsigned*)(ws + FLAGS_OFF);
    float* out_hidden = out + LOGITS_N;

    // 1) initial hidden state -> slot 0; zero flags
    init_state_k<<<dim3((BH + 255) / 256), dim3(256), 0, stream>>>(hidden, h0_all, h1_all, flags);

    // 2) pre0 = emb[tok] @ W_ih0^T + b_ih0 + b_hh0   (M=8192, N=512, K=512)
    gemm_nt_k<<<dim3(64, 4), dim3(256), 0, stream>>>(
        emb, inputs, W_ih0, b_ih0, b_hh0, pre0, HID, EMBD, HID);

    // 3) recurrence (dataflow, per-block flags; bypass-staged consumer reads)
    const float* pre0_c = pre0;
    void* kargs[] = { (void*)&pre0_c, (void*)&W_hh0, (void*)&W_in, (void*)&b_in,
                      (void*)&W_hh, (void*)&b_hh, (void*)&h0_all, (void*)&h1_all,
                      (void*)&flags };
    hipLaunchCooperativeKernel((const void*)recurrence_k, dim3(512), dim3(256),
                               kargs, 0, stream);

    // 4) final hidden -> d_out tail (stream-ordered after recurrence)
    copy_out_k<<<dim3(256), dim3(256), 0, stream>>>(h0_all, h1_all, out_hidden);

    // 5) logits = h1_all[1..128] @ Wy^T + by   (M=8192, N=10000, K=512)
    gemm_nt_k<<<dim3(64, 79), dim3(256), 0, stream>>>(
        h1_all + BH, nullptr, Wy, nullptr, by, out, VOC, HID, VOC);
}

// Round 5
// 1443.875 us; speedup vs baseline: 7.5682x; 2.1437x over previous
//
#include <hip/hip_runtime.h>
#include <hip/hip_bf16.h>

#define SEQ 128
#define BAT 64
#define VOC 10000
#define EMBD 512
#define HID 512
#define BH (BAT*HID)                  // 32768
// workspace layout (floats)
#define PRE0_OFF 0
#define H0_OFF   ((size_t)SEQ*BH)                 // pre0: 128*BH
#define H1_OFF   (H0_OFF + (size_t)(SEQ+1)*BH)
#define FLAGS_OFF (H1_OFF + (size_t)(SEQ+1)*BH)   // 256 uint flags
#define CONV_OFF (FLAGS_OFF + 256)                // bf16 hi/lo split arrays
#define LOGITS_N ((size_t)SEQ*BAT*VOC)            // 81,920,000 (in d_out)
// conv area: h_hi/h_lo: 2*4,194,304 ushorts; w_hi/w_lo: 2*5,120,000 ushorts
#define CONV_FLOATS 9314304ull
#define WS_NEED_FLOATS (CONV_OFF + CONV_FLOATS)

typedef __attribute__((ext_vector_type(8))) __bf16 bf16x8;
typedef __attribute__((ext_vector_type(4))) float f32x4;

__global__ __launch_bounds__(256) void init_state_k(const float* __restrict__ hidden,
                                                    float* __restrict__ h0_0,
                                                    float* __restrict__ h1_0,
                                                    unsigned* __restrict__ flags) {
    int i = blockIdx.x * 256 + threadIdx.x;
    if (i < 256) flags[i] = 0u;
    if (i < BH) { h0_0[i] = hidden[i]; h1_0[i] = hidden[BH + i]; }
}

// fp32 GEMM: C[M,N] = A'[M,K] @ Bm[N,K]^T (+bias0+bias1); used for pre0 and as
// logits fallback when ws is too small for the bf16-split path.
__global__ __launch_bounds__(256) void gemm_nt_k(
    const float* __restrict__ A, const int* __restrict__ tok,
    const float* __restrict__ Bm,
    const float* __restrict__ bias0, const float* __restrict__ bias1,
    float* __restrict__ C, int N, int K, int ldc)
{
    __shared__ float As[32][132];
    __shared__ float Bs[32][132];
    __shared__ int toks[128];

    const int tid = threadIdx.x;
    const int r0 = blockIdx.x * 128;
    const int c0 = blockIdx.y * 128;

    if (tok != nullptr && tid < 128) toks[tid] = tok[r0 + tid];
    __syncthreads();

    const int tn = tid & 15;
    const int tm = tid >> 4;
    const int m0 = tm * 8, n0 = tn * 8;

    float acc[8][8];
#pragma unroll
    for (int i = 0; i < 8; ++i)
#pragma unroll
        for (int j = 0; j < 8; ++j) acc[i][j] = 0.f;

    for (int k0 = 0; k0 < K; k0 += 32) {
#pragma unroll
        for (int p = 0; p < 4; ++p) {
            int idx = p * 256 + tid;
            int row = idx >> 3;
            int kq  = (idx & 7) << 2;
            size_t arow = tok ? (size_t)toks[row] : (size_t)(r0 + row);
            float4 a = *(const float4*)(A + arow * (size_t)K + k0 + kq);
            As[kq+0][row] = a.x; As[kq+1][row] = a.y;
            As[kq+2][row] = a.z; As[kq+3][row] = a.w;
            int gc = c0 + row;
            float4 b = make_float4(0.f, 0.f, 0.f, 0.f);
            if (gc < N) b = *(const float4*)(Bm + (size_t)gc * K + k0 + kq);
            Bs[kq+0][row] = b.x; Bs[kq+1][row] = b.y;
            Bs[kq+2][row] = b.z; Bs[kq+3][row] = b.w;
        }
        __syncthreads();
#pragma unroll 8
        for (int k = 0; k < 32; ++k) {
            float4 a0 = *(const float4*)&As[k][m0];
            float4 a1 = *(const float4*)&As[k][m0 + 4];
            float4 b0 = *(const float4*)&Bs[k][n0];
            float4 b1 = *(const float4*)&Bs[k][n0 + 4];
            float am[8] = {a0.x,a0.y,a0.z,a0.w,a1.x,a1.y,a1.z,a1.w};
            float bn[8] = {b0.x,b0.y,b0.z,b0.w,b1.x,b1.y,b1.z,b1.w};
#pragma unroll
            for (int i = 0; i < 8; ++i)
#pragma unroll
                for (int j = 0; j < 8; ++j) acc[i][j] += am[i] * bn[j];
        }
        __syncthreads();
    }

    float bj[8];
#pragma unroll
    for (int j = 0; j < 8; ++j) {
        int c = c0 + n0 + j;
        float v = 0.f;
        if (c < N) {
            if (bias0) v += bias0[c];
            if (bias1) v += bias1[c];
        }
        bj[j] = v;
    }
    const bool full = (c0 + 128 <= N);
#pragma unroll
    for (int i = 0; i < 8; ++i) {
        size_t r = (size_t)(r0 + m0 + i);
        float* crow = C + r * (size_t)ldc + c0 + n0;
        if (full) {
            float4 v0 = make_float4(acc[i][0]+bj[0], acc[i][1]+bj[1],
                                    acc[i][2]+bj[2], acc[i][3]+bj[3]);
            float4 v1 = make_float4(acc[i][4]+bj[4], acc[i][5]+bj[5],
                                    acc[i][6]+bj[6], acc[i][7]+bj[7]);
            *(float4*)(crow)     = v0;
            *(float4*)(crow + 4) = v1;
        } else {
#pragma unroll
            for (int j = 0; j < 8; ++j) {
                int c = c0 + n0 + j;
                if (c < N) crow[j] = acc[i][j] + bj[j];
            }
        }
    }
}

// ---------------- recurrence v3 ----------------
// 192 blocks x 512 threads (coop launch = co-residency only).
// blocks 0..63   (L1): groups g=blk/16 (16 batches), jb=blk%16 (32 j-rows).
// blocks 64..191 (L2): groups g=idx/32 (16 batches), jb=idx%32 (16 j-rows).
// Wave-tile 8b x 8j; lane owns an 8-k span; W resident in VGPRs all 128 steps.
// Butterfly all-reduce over the 64 k-lanes; lane ends owning pair bitrev6(lane).

#define BFLY(S, N)                                                     \
    {                                                                  \
        _Pragma("unroll")                                              \
        for (int i = 0; i < N; ++i) {                                  \
            float lo_ = a[i], hi_ = a[i + N];                          \
            float send_ = (lane & S) ? lo_ : hi_;                      \
            float recv_ = __shfl_xor(send_, S);                        \
            a[i] = ((lane & S) ? hi_ : lo_) + recv_;                   \
        }                                                              \
    }

__global__ __launch_bounds__(512) void recurrence_k(
    const float* __restrict__ pre0, const float* __restrict__ W_hh0,
    const float* __restrict__ W_in, const float* __restrict__ b_in,
    const float* __restrict__ W_hh, const float* __restrict__ b_hh,
    float* __restrict__ h0_all, float* __restrict__ h1_all,
    unsigned* __restrict__ flags)
{
    __shared__ float xs[16384];   // 64 KB: [h0 8192][h1 8192] (L1 uses first half)

    const int tid  = threadIdx.x;
    const int lane = tid & 63;
    const int wv   = tid >> 6;
    const int p = ((lane&1)<<5)|((lane&2)<<3)|((lane&4)<<1)
                | ((lane&8)>>1)|((lane&16)>>3)|((lane&32)>>5);  // bitrev6
    const int b_own = p >> 3, j_own = p & 7;

    unsigned* fl1 = flags;
    unsigned* fl2 = flags + 64;

    float4 wr[8][2];
    float a[64];

    if (blockIdx.x < 64) {                     // ---- layer 1 ----
        const int g = blockIdx.x >> 4, jb = blockIdx.x & 15;
        const int bt = wv & 1, jt = wv >> 1;
        const size_t win = (size_t)(g << 4) * HID;
#pragma unroll
        for (int jj = 0; jj < 8; ++jj) {
            const float* wp = W_hh0 + (size_t)(jb*32 + jt*8 + jj) * HID + lane*8;
            wr[jj][0] = *(const float4*)wp;
            wr[jj][1] = *(const float4*)(wp + 4);
        }
        const unsigned* grp = fl1 + (g << 4);
        unsigned* myf = fl1 + (g << 4) + jb;
        const int bg = (g << 4) + (bt << 3) + b_own;
        const int jg = jb*32 + jt*8 + j_own;

        for (unsigned t = 1; t <= SEQ; ++t) {
            float pf = pre0[(size_t)(t-1)*BH + (size_t)bg*HID + jg];  // indep prefetch
            for (;;) {
                unsigned v = __hip_atomic_load(&grp[lane & 15], __ATOMIC_RELAXED,
                                               __HIP_MEMORY_SCOPE_AGENT);
                if (__ballot(v < (t - 1)) == 0ull) break;
            }
            __syncthreads();
            {   // stage h0[t-1][16 rows] -> xs (coherence-point bypass)
                const float4* src = (const float4*)(h0_all + (size_t)(t-1)*BH + win);
                float4 r0_, r1_, r2_, r3_;
                asm volatile("global_load_dwordx4 %0, %1, off sc0 sc1" : "=v"(r0_) : "v"(src + tid));
                asm volatile("global_load_dwordx4 %0, %1, off sc0 sc1" : "=v"(r1_) : "v"(src + tid + 512));
                asm volatile("global_load_dwordx4 %0, %1, off sc0 sc1" : "=v"(r2_) : "v"(src + tid + 1024));
                asm volatile("global_load_dwordx4 %0, %1, off sc0 sc1" : "=v"(r3_) : "v"(src + tid + 1536));
                asm volatile("s_waitcnt vmcnt(0)" ::: "memory");
                __builtin_amdgcn_sched_barrier(0);
                float4* dst = (float4*)xs;
                dst[tid] = r0_; dst[tid+512] = r1_; dst[tid+1024] = r2_; dst[tid+1536] = r3_;
            }
            __syncthreads();
#pragma unroll
            for (int i = 0; i < 64; ++i) a[i] = 0.f;
#pragma unroll
            for (int b = 0; b < 8; ++b) {
                const int row = (bt << 3) + b;
                float4 ha = *(const float4*)&xs[row*512 + lane*8];
                float4 hb = *(const float4*)&xs[row*512 + lane*8 + 4];
#pragma unroll
                for (int jj = 0; jj < 8; ++jj) {
                    a[b*8+jj] += ha.x*wr[jj][0].x + ha.y*wr[jj][0].y
                               + ha.z*wr[jj][0].z + ha.w*wr[jj][0].w
                               + hb.x*wr[jj][1].x + hb.y*wr[jj][1].y
                               + hb.z*wr[jj][1].z + hb.w*wr[jj][1].w;
                }
            }
            BFLY(1,32) BFLY(2,16) BFLY(4,8) BFLY(8,4) BFLY(16,2) BFLY(32,1)
            float v = tanhf(a[0] + pf);
            __hip_atomic_store(&h0_all[(size_t)t*BH + (size_t)bg*HID + jg], v,
                               __ATOMIC_RELAXED, __HIP_MEMORY_SCOPE_AGENT);
            asm volatile("s_waitcnt vmcnt(0)" ::: "memory");
            __syncthreads();
            if (tid == 0) __hip_atomic_store(myf, t, __ATOMIC_RELAXED,
                                             __HIP_MEMORY_SCOPE_AGENT);
        }
    } else {                                   // ---- layer 2 ----
        const int idx = blockIdx.x - 64;
        const int g = idx >> 5, jb = idx & 31;
        const int bt = wv & 1, jt = (wv >> 1) & 1, kt = wv >> 2;
        const size_t win = (size_t)(g << 4) * HID;
        const float* Wmat = kt ? W_hh : W_in;
#pragma unroll
        for (int jj = 0; jj < 8; ++jj) {
            const float* wp = Wmat + (size_t)(jb*16 + jt*8 + jj) * HID + lane*8;
            wr[jj][0] = *(const float4*)wp;
            wr[jj][1] = *(const float4*)(wp + 4);
        }
        const unsigned* grpA = fl1 + (g << 4);
        const unsigned* grpB = fl2 + (g << 5);
        unsigned* myf = fl2 + (g << 5) + jb;
        const int bg = (g << 4) + (bt << 3) + b_own;
        const int jg = jb*16 + jt*8 + j_own;
        const float bias = b_in[jg] + b_hh[jg];
        const int scx = (wv & 3) * 64 + lane;

        for (unsigned t = 1; t <= SEQ; ++t) {
            for (;;) {
                unsigned v1 = __hip_atomic_load(&grpA[lane & 15], __ATOMIC_RELAXED,
                                                __HIP_MEMORY_SCOPE_AGENT);
                unsigned v2 = __hip_atomic_load(&grpB[lane & 31], __ATOMIC_RELAXED,
                                                __HIP_MEMORY_SCOPE_AGENT);
                if (__ballot(v1 < t) == 0ull && __ballot(v2 < (t - 1)) == 0ull) break;
            }
            __syncthreads();
            {   // stage h0[t] and h1[t-1] (16 rows each)
                const int q = tid & 255;
                const float4* src = (tid < 256)
                    ? (const float4*)(h0_all + (size_t)t*BH + win)
                    : (const float4*)(h1_all + (size_t)(t-1)*BH + win);
                float4 rr[8];
#pragma unroll
                for (int i = 0; i < 8; ++i)
                    asm volatile("global_load_dwordx4 %0, %1, off sc0 sc1"
                                 : "=v"(rr[i]) : "v"(src + q + i*256));
                asm volatile("s_waitcnt vmcnt(0)" ::: "memory");
                __builtin_amdgcn_sched_barrier(0);
                float4* dst = (float4*)(xs + ((tid < 256) ? 0 : 8192));
#pragma unroll
                for (int i = 0; i < 8; ++i) dst[q + i*256] = rr[i];
            }
            __syncthreads();
#pragma unroll
            for (int i = 0; i < 64; ++i) a[i] = 0.f;
            const float* xsrc = xs + (kt ? 8192 : 0);
#pragma unroll
            for (int b = 0; b < 8; ++b) {
                const int row = (bt << 3) + b;
                float4 ha = *(const float4*)&xsrc[row*512 + lane*8];
                float4 hb = *(const float4*)&xsrc[row*512 + lane*8 + 4];
#pragma unroll
                for (int jj = 0; jj < 8; ++jj) {
                    a[b*8+jj] += ha.x*wr[jj][0].x + ha.y*wr[jj][0].y
                               + ha.z*wr[jj][0].z + ha.w*wr[jj][0].w
                               + hb.x*wr[jj][1].x + hb.y*wr[jj][1].y
                               + hb.z*wr[jj][1].z + hb.w*wr[jj][1].w;
                }
            }
            BFLY(1,32) BFLY(2,16) BFLY(4,8) BFLY(8,4) BFLY(16,2) BFLY(32,1)
            __syncthreads();
            if (kt) xs[scx] = a[0];            // scratch: reuse xs[0..255]
            __syncthreads();
            if (!kt) {
                float v = tanhf(a[0] + xs[scx] + bias);
                __hip_atomic_store(&h1_all[(size_t)t*BH + (size_t)bg*HID + jg], v,
                                   __ATOMIC_RELAXED, __HIP_MEMORY_SCOPE_AGENT);
            }
            asm volatile("s_waitcnt vmcnt(0)" ::: "memory");
            __syncthreads();
            if (tid == 0) __hip_atomic_store(myf, t, __ATOMIC_RELAXED,
                                             __HIP_MEMORY_SCOPE_AGENT);
        }
    }
}

__global__ __launch_bounds__(256) void copy_out_k(const float* __restrict__ h0_all,
                                                  const float* __restrict__ h1_all,
                                                  float* __restrict__ out_hidden) {
    int g = blockIdx.x * 256 + threadIdx.x;
    if (g < BH)            out_hidden[g] = h0_all[(size_t)SEQ * BH + g];
    else if (g < 2 * BH)   out_hidden[g] = h1_all[(size_t)SEQ * BH + (g - BH)];
}

// ---------------- bf16 split (hi/lo) + MFMA logits GEMM ----------------

__device__ __forceinline__ unsigned short bf16_rne(float x) {
    unsigned u = __float_as_uint(x);
    unsigned r = u + 0x7fffu + ((u >> 16) & 1u);
    return (unsigned short)(r >> 16);
}

__global__ __launch_bounds__(256) void split_bf16_k(const float* __restrict__ src,
                                                    unsigned short* __restrict__ hi,
                                                    unsigned short* __restrict__ lo,
                                                    int n4) {
    int i = blockIdx.x * 256 + threadIdx.x;
    if (i >= n4) return;
    float4 v = ((const float4*)src)[i];
    ushort4 h4, l4;
    float f;
    h4.x = bf16_rne(v.x); f = __uint_as_float((unsigned)h4.x << 16); l4.x = bf16_rne(v.x - f);
    h4.y = bf16_rne(v.y); f = __uint_as_float((unsigned)h4.y << 16); l4.y = bf16_rne(v.y - f);
    h4.z = bf16_rne(v.z); f = __uint_as_float((unsigned)h4.z << 16); l4.z = bf16_rne(v.z - f);
    h4.w = bf16_rne(v.w); f = __uint_as_float((unsigned)h4.w << 16); l4.w = bf16_rne(v.w - f);
    ((ushort4*)hi)[i] = h4;
    ((ushort4*)lo)[i] = l4;
}

// C[8192,VOC] = A[8192,512] @ B[VOC,512]^T + by, with A,B given as bf16 hi/lo
// pairs; acc = Ah*Bh + Ah*Bl + Al*Bh (fp32 MFMA accumulate). 128x128 tile,
// BK=64, XOR-swizzled LDS, mfma_f32_16x16x32_bf16.
__global__ __launch_bounds__(256) void logits_mfma_k(
    const unsigned short* __restrict__ Ahg, const unsigned short* __restrict__ Alg,
    const unsigned short* __restrict__ Bhg, const unsigned short* __restrict__ Blg,
    const float* __restrict__ by, float* __restrict__ C)
{
    __shared__ __align__(16) unsigned short sAh[128*64];
    __shared__ __align__(16) unsigned short sAl[128*64];
    __shared__ __align__(16) unsigned short sBh[128*64];
    __shared__ __align__(16) unsigned short sBl[128*64];

    const int tid = threadIdx.x;
    const int r0 = blockIdx.x * 128, c0 = blockIdx.y * 128;
    const int lane = tid & 63, wv = tid >> 6;
    const int mh = wv >> 1, nh = wv & 1;

    f32x4 acc[4][4];
#pragma unroll
    for (int i = 0; i < 4; ++i)
#pragma unroll
        for (int j = 0; j < 4; ++j) acc[i][j] = (f32x4){0.f, 0.f, 0.f, 0.f};

    const int srow = tid >> 1, shalf = tid & 1;
    const size_t abase = (size_t)(r0 + srow) * 512 + shalf * 32;
    const int brow = c0 + srow;
    const bool bok = brow < VOC;
    const size_t bbase = (size_t)(bok ? brow : 0) * 512 + shalf * 32;
    const int woff = srow * 64;
    const int swz = srow & 7;

    for (int k0 = 0; k0 < 512; k0 += 64) {
        uint4 vah[4], val_[4], vbh[4], vbl[4];
#pragma unroll
        for (int g = 0; g < 4; ++g) {
            vah[g]  = *(const uint4*)(Ahg + abase + k0 + g*8);
            val_[g] = *(const uint4*)(Alg + abase + k0 + g*8);
            if (bok) {
                vbh[g] = *(const uint4*)(Bhg + bbase + k0 + g*8);
                vbl[g] = *(const uint4*)(Blg + bbase + k0 + g*8);
            } else {
                vbh[g] = (uint4){0,0,0,0};
                vbl[g] = (uint4){0,0,0,0};
            }
        }
        __syncthreads();
#pragma unroll
        for (int g = 0; g < 4; ++g) {
            int off = woff + (((shalf*4 + g) ^ swz) * 8);
            *(uint4*)&sAh[off] = vah[g];
            *(uint4*)&sAl[off] = val_[g];
            *(uint4*)&sBh[off] = vbh[g];
            *(uint4*)&sBl[off] = vbl[g];
        }
        __syncthreads();
#pragma unroll
        for (int c = 0; c < 2; ++c) {
            const int ks = ((c*4 + (lane >> 4)) ^ (lane & 7)) * 8;
            bf16x8 fAh[4], fAl[4], fBh[4], fBl[4];
#pragma unroll
            for (int mi = 0; mi < 4; ++mi) {
                int ro = (mh*64 + mi*16 + (lane & 15)) * 64;
                fAh[mi] = *(const bf16x8*)&sAh[ro + ks];
                fAl[mi] = *(const bf16x8*)&sAl[ro + ks];
            }
#pragma unroll
            for (int ni = 0; ni < 4; ++ni) {
                int ro = (nh*64 + ni*16 + (lane & 15)) * 64;
                fBh[ni] = *(const bf16x8*)&sBh[ro + ks];
                fBl[ni] = *(const bf16x8*)&sBl[ro + ks];
            }
#pragma unroll
            for (int mi = 0; mi < 4; ++mi)
#pragma unroll
                for (int ni = 0; ni < 4; ++ni) {
                    acc[mi][ni] = __builtin_amdgcn_mfma_f32_16x16x32_bf16(
                        fAh[mi], fBh[ni], acc[mi][ni], 0, 0, 0);
                    acc[mi][ni] = __builtin_amdgcn_mfma_f32_16x16x32_bf16(
                        fAh[mi], fBl[ni], acc[mi][ni], 0, 0, 0);
                    acc[mi][ni] = __builtin_amdgcn_mfma_f32_16x16x32_bf16(
                        fAl[mi], fBh[ni], acc[mi][ni], 0, 0, 0);
                }
        }
        __syncthreads();
    }

#pragma unroll
    for (int ni = 0; ni < 4; ++ni) {
        int gcol = c0 + nh*64 + ni*16 + (lane & 15);
        bool ok = gcol < VOC;
        float bias = ok ? by[gcol] : 0.f;
#pragma unroll
        for (int mi = 0; mi < 4; ++mi) {
            int grow = r0 + mh*64 + mi*16 + ((lane >> 4) << 2);
#pragma unroll
            for (int r = 0; r < 4; ++r)
                if (ok) C[(size_t)(grow + r) * VOC + gcol] = acc[mi][ni][r] + bias;
        }
    }
}

extern "C" void kernel_launch(void* const* d_in, const int* in_sizes, int n_in,
                              void* d_out, int out_size, void* d_ws, size_t ws_size,
                              hipStream_t stream) {
    const int*   inputs = (const int*)d_in[0];
    const float* hidden = (const float*)d_in[1];
    const float* emb    = (const float*)d_in[2];
    const float* W_ih0  = (const float*)d_in[3];
    const float* b_ih0  = (const float*)d_in[4];
    const float* W_hh0  = (const float*)d_in[5];
    const float* b_hh0  = (const float*)d_in[6];
    const float* W_in   = (const float*)d_in[7];
    const float* b_in   = (const float*)d_in[8];
    const float* W_hh   = (const float*)d_in[9];
    const float* b_hh   = (const float*)d_in[10];
    const float* Wy     = (const float*)d_in[11];
    const float* by     = (const float*)d_in[12];
    float* out = (float*)d_out;

    float* ws     = (float*)d_ws;
    float* pre0   = ws + PRE0_OFF;
    float* h0_all = ws + H0_OFF;
    float* h1_all = ws + H1_OFF;
    unsigned* flags = (unsigned*)(ws + FLAGS_OFF);
    float* out_hidden = out + LOGITS_N;

    // 1) initial hidden state -> slot 0; zero flags
    init_state_k<<<dim3((BH + 255) / 256), dim3(256), 0, stream>>>(hidden, h0_all, h1_all, flags);

    // 2) pre0 = emb[tok] @ W_ih0^T + b_ih0 + b_hh0   (M=8192, N=512, K=512)
    gemm_nt_k<<<dim3(64, 4), dim3(256), 0, stream>>>(
        emb, inputs, W_ih0, b_ih0, b_hh0, pre0, HID, EMBD, HID);

    // 3) recurrence v3 (dataflow flags, W-in-VGPR, butterfly reduce)
    const float* pre0_c = pre0;
    void* kargs[] = { (void*)&pre0_c, (void*)&W_hh0, (void*)&W_in, (void*)&b_in,
                      (void*)&W_hh, (void*)&b_hh, (void*)&h0_all, (void*)&h1_all,
                      (void*)&flags };
    hipLaunchCooperativeKernel((const void*)recurrence_k, dim3(192), dim3(512),
                               kargs, 0, stream);

    // 4) final hidden -> d_out tail
    copy_out_k<<<dim3(256), dim3(256), 0, stream>>>(h0_all, h1_all, out_hidden);

    // 5) logits = h1[1..128] @ Wy^T + by  (M=8192, N=10000, K=512)
    if (ws_size >= WS_NEED_FLOATS * 4ull) {
        unsigned short* h_hi = (unsigned short*)(ws + CONV_OFF);
        unsigned short* h_lo = h_hi + (size_t)8192 * 512;
        unsigned short* w_hi = h_lo + (size_t)8192 * 512;
        unsigned short* w_lo = w_hi + (size_t)VOC * 512;
        split_bf16_k<<<dim3(4096), dim3(256), 0, stream>>>(h1_all + BH, h_hi, h_lo, 8192*512/4);
        split_bf16_k<<<dim3(5000), dim3(256), 0, stream>>>(Wy, w_hi, w_lo, VOC*512/4);
        logits_mfma_k<<<dim3(64, 79), dim3(256), 0, stream>>>(h_hi, h_lo, w_hi, w_lo, by, out);
    } else {
        gemm_nt_k<<<dim3(64, 79), dim3(256), 0, stream>>>(
            h1_all + BH, nullptr, Wy, nullptr, by, out, VOC, HID, VOC);
    }
}

// Round 6
// 1437.176 us; speedup vs baseline: 7.6035x; 1.0047x over previous
//
#include <hip/hip_runtime.h>
#include <hip/hip_bf16.h>

#define SEQ 128
#define BAT 64
#define VOC 10000
#define EMBD 512
#define HID 512
#define BH (BAT*HID)                  // 32768
// workspace layout (floats)
#define PRE0_OFF 0
#define H0_OFF   ((size_t)SEQ*BH)                 // pre0: 128*BH
#define H1_OFF   (H0_OFF + (size_t)(SEQ+1)*BH)
#define FLAGS_OFF (H1_OFF + (size_t)(SEQ+1)*BH)   // 256 uint flags
#define CONV_OFF (FLAGS_OFF + 256)                // bf16 split arrays (overlaid)
#define LOGITS_N ((size_t)SEQ*BAT*VOC)            // 81,920,000 (in d_out)
// conv region (ushort offsets from conv base), two overlaid phases:
//  phase B (pre0):   emb_hi@0 (5.12M), emb_lo@5.12M (5.12M), wih0_hi@10.24M (262144)
//  phase A (logits): h_hi@0 (4.19M),   h_lo@4.19M (4.19M),   wy_hi@8.39M (5.12M)
#define CONV_USHORTS 13508608ull
#define WS_NEED_FLOATS (CONV_OFF + CONV_USHORTS/2)

typedef __attribute__((ext_vector_type(8))) __bf16 bf16x8;
typedef __attribute__((ext_vector_type(4))) float f32x4;

__global__ __launch_bounds__(256) void init_state_k(const float* __restrict__ hidden,
                                                    float* __restrict__ h0_0,
                                                    float* __restrict__ h1_0,
                                                    unsigned* __restrict__ flags) {
    int i = blockIdx.x * 256 + threadIdx.x;
    if (i < 256) flags[i] = 0u;
    if (i < BH) { h0_0[i] = hidden[i]; h1_0[i] = hidden[BH + i]; }
}

// fp32 GEMM fallback (used only if ws too small for bf16-split path).
__global__ __launch_bounds__(256) void gemm_nt_k(
    const float* __restrict__ A, const int* __restrict__ tok,
    const float* __restrict__ Bm,
    const float* __restrict__ bias0, const float* __restrict__ bias1,
    float* __restrict__ C, int N, int K, int ldc)
{
    __shared__ float As[32][132];
    __shared__ float Bs[32][132];
    __shared__ int toks[128];

    const int tid = threadIdx.x;
    const int r0 = blockIdx.x * 128;
    const int c0 = blockIdx.y * 128;

    if (tok != nullptr && tid < 128) toks[tid] = tok[r0 + tid];
    __syncthreads();

    const int tn = tid & 15;
    const int tm = tid >> 4;
    const int m0 = tm * 8, n0 = tn * 8;

    float acc[8][8];
#pragma unroll
    for (int i = 0; i < 8; ++i)
#pragma unroll
        for (int j = 0; j < 8; ++j) acc[i][j] = 0.f;

    for (int k0 = 0; k0 < K; k0 += 32) {
#pragma unroll
        for (int p = 0; p < 4; ++p) {
            int idx = p * 256 + tid;
            int row = idx >> 3;
            int kq  = (idx & 7) << 2;
            size_t arow = tok ? (size_t)toks[row] : (size_t)(r0 + row);
            float4 a = *(const float4*)(A + arow * (size_t)K + k0 + kq);
            As[kq+0][row] = a.x; As[kq+1][row] = a.y;
            As[kq+2][row] = a.z; As[kq+3][row] = a.w;
            int gc = c0 + row;
            float4 b = make_float4(0.f, 0.f, 0.f, 0.f);
            if (gc < N) b = *(const float4*)(Bm + (size_t)gc * K + k0 + kq);
            Bs[kq+0][row] = b.x; Bs[kq+1][row] = b.y;
            Bs[kq+2][row] = b.z; Bs[kq+3][row] = b.w;
        }
        __syncthreads();
#pragma unroll 8
        for (int k = 0; k < 32; ++k) {
            float4 a0 = *(const float4*)&As[k][m0];
            float4 a1 = *(const float4*)&As[k][m0 + 4];
            float4 b0 = *(const float4*)&Bs[k][n0];
            float4 b1 = *(const float4*)&Bs[k][n0 + 4];
            float am[8] = {a0.x,a0.y,a0.z,a0.w,a1.x,a1.y,a1.z,a1.w};
            float bn[8] = {b0.x,b0.y,b0.z,b0.w,b1.x,b1.y,b1.z,b1.w};
#pragma unroll
            for (int i = 0; i < 8; ++i)
#pragma unroll
                for (int j = 0; j < 8; ++j) acc[i][j] += am[i] * bn[j];
        }
        __syncthreads();
    }

    const bool full = (c0 + 128 <= N);
#pragma unroll
    for (int i = 0; i < 8; ++i) {
        size_t r = (size_t)(r0 + m0 + i);
        float* crow = C + r * (size_t)ldc;
#pragma unroll
        for (int j = 0; j < 8; ++j) {
            int c = c0 + n0 + j;
            if (full || c < N) {
                float v = acc[i][j];
                if (bias0) v += bias0[c];
                if (bias1) v += bias1[c];
                crow[c] = v;
            }
        }
    }
}

// ---------------- recurrence v4 ----------------
// 192 blocks x 512 threads (coop launch = co-residency only).
// blocks 0..63   (L1): groups g=blk/16 (16 batches), jb=blk%16 (32 j-rows).
// blocks 64..191 (L2): groups g=idx/32 (16 batches), jb=idx%32 (16 j-rows).
// Wave-tile 8b x 8j; lane owns k-span {4L..4L+3} U {256+4L..+3} -> every
// ds_read_b128 quarter-wave covers all 32 banks at 2 dwords/bank (conflict-
// free minimum). W resident in VGPRs all 128 steps. Butterfly all-reduce.

#define BFLY(S, N)                                                     \
    {                                                                  \
        _Pragma("unroll")                                              \
        for (int i = 0; i < N; ++i) {                                  \
            float lo_ = a[i], hi_ = a[i + N];                          \
            float send_ = (lane & S) ? lo_ : hi_;                      \
            float recv_ = __shfl_xor(send_, S);                        \
            a[i] = ((lane & S) ? hi_ : lo_) + recv_;                   \
        }                                                              \
    }

__global__ __launch_bounds__(512) void recurrence_k(
    const float* __restrict__ pre0, const float* __restrict__ W_hh0,
    const float* __restrict__ W_in, const float* __restrict__ b_in,
    const float* __restrict__ W_hh, const float* __restrict__ b_hh,
    float* __restrict__ h0_all, float* __restrict__ h1_all,
    unsigned* __restrict__ flags)
{
    __shared__ float xs[16384];   // 64 KB: [h0 8192][h1 8192] (L1 uses first half)

    const int tid  = threadIdx.x;
    const int lane = tid & 63;
    const int wv   = tid >> 6;
    const int p = ((lane&1)<<5)|((lane&2)<<3)|((lane&4)<<1)
                | ((lane&8)>>1)|((lane&16)>>3)|((lane&32)>>5);  // bitrev6
    const int b_own = p >> 3, j_own = p & 7;

    unsigned* fl1 = flags;
    unsigned* fl2 = flags + 64;

    float4 wr[8][2];
    float a[64];

    if (blockIdx.x < 64) {                     // ---- layer 1 ----
        const int g = blockIdx.x >> 4, jb = blockIdx.x & 15;
        const int bt = wv & 1, jt = wv >> 1;
        const size_t win = (size_t)(g << 4) * HID;
#pragma unroll
        for (int jj = 0; jj < 8; ++jj) {
            const float* wp = W_hh0 + (size_t)(jb*32 + jt*8 + jj) * HID;
            wr[jj][0] = *(const float4*)(wp + lane*4);
            wr[jj][1] = *(const float4*)(wp + 256 + lane*4);
        }
        const unsigned* grp = fl1 + (g << 4);
        unsigned* myf = fl1 + (g << 4) + jb;
        const int bg = (g << 4) + (bt << 3) + b_own;
        const int jg = jb*32 + jt*8 + j_own;

        for (unsigned t = 1; t <= SEQ; ++t) {
            float pf = pre0[(size_t)(t-1)*BH + (size_t)bg*HID + jg];  // indep prefetch
            for (;;) {
                unsigned v = __hip_atomic_load(&grp[lane & 15], __ATOMIC_RELAXED,
                                               __HIP_MEMORY_SCOPE_AGENT);
                if (__ballot(v < (t - 1)) == 0ull) break;
            }
            __syncthreads();
            {   // stage h0[t-1][16 rows] -> xs (coherence-point bypass)
                const float4* src = (const float4*)(h0_all + (size_t)(t-1)*BH + win);
                float4 r0_, r1_, r2_, r3_;
                asm volatile("global_load_dwordx4 %0, %1, off sc0 sc1" : "=v"(r0_) : "v"(src + tid));
                asm volatile("global_load_dwordx4 %0, %1, off sc0 sc1" : "=v"(r1_) : "v"(src + tid + 512));
                asm volatile("global_load_dwordx4 %0, %1, off sc0 sc1" : "=v"(r2_) : "v"(src + tid + 1024));
                asm volatile("global_load_dwordx4 %0, %1, off sc0 sc1" : "=v"(r3_) : "v"(src + tid + 1536));
                asm volatile("s_waitcnt vmcnt(0)" ::: "memory");
                __builtin_amdgcn_sched_barrier(0);
                float4* dst = (float4*)xs;
                dst[tid] = r0_; dst[tid+512] = r1_; dst[tid+1024] = r2_; dst[tid+1536] = r3_;
            }
            __syncthreads();
#pragma unroll
            for (int i = 0; i < 64; ++i) a[i] = 0.f;
#pragma unroll
            for (int b = 0; b < 8; ++b) {
                const int row = (bt << 3) + b;
                float4 ha = *(const float4*)&xs[row*512 + lane*4];
                float4 hb = *(const float4*)&xs[row*512 + 256 + lane*4];
#pragma unroll
                for (int jj = 0; jj < 8; ++jj) {
                    a[b*8+jj] += ha.x*wr[jj][0].x + ha.y*wr[jj][0].y
                               + ha.z*wr[jj][0].z + ha.w*wr[jj][0].w
                               + hb.x*wr[jj][1].x + hb.y*wr[jj][1].y
                               + hb.z*wr[jj][1].z + hb.w*wr[jj][1].w;
                }
            }
            BFLY(1,32) BFLY(2,16) BFLY(4,8) BFLY(8,4) BFLY(16,2) BFLY(32,1)
            float v = tanhf(a[0] + pf);
            __hip_atomic_store(&h0_all[(size_t)t*BH + (size_t)bg*HID + jg], v,
                               __ATOMIC_RELAXED, __HIP_MEMORY_SCOPE_AGENT);
            asm volatile("s_waitcnt vmcnt(0)" ::: "memory");
            __syncthreads();
            if (tid == 0) __hip_atomic_store(myf, t, __ATOMIC_RELAXED,
                                             __HIP_MEMORY_SCOPE_AGENT);
        }
    } else {                                   // ---- layer 2 ----
        const int idx = blockIdx.x - 64;
        const int g = idx >> 5, jb = idx & 31;
        const int bt = wv & 1, jt = (wv >> 1) & 1, kt = wv >> 2;
        const size_t win = (size_t)(g << 4) * HID;
        const float* Wmat = kt ? W_hh : W_in;
#pragma unroll
        for (int jj = 0; jj < 8; ++jj) {
            const float* wp = Wmat + (size_t)(jb*16 + jt*8 + jj) * HID;
            wr[jj][0] = *(const float4*)(wp + lane*4);
            wr[jj][1] = *(const float4*)(wp + 256 + lane*4);
        }
        const unsigned* grpA = fl1 + (g << 4);
        const unsigned* grpB = fl2 + (g << 5);
        unsigned* myf = fl2 + (g << 5) + jb;
        const int bg = (g << 4) + (bt << 3) + b_own;
        const int jg = jb*16 + jt*8 + j_own;
        const float bias = b_in[jg] + b_hh[jg];
        const int scx = (wv & 3) * 64 + lane;

        for (unsigned t = 1; t <= SEQ; ++t) {
            for (;;) {
                unsigned v1 = __hip_atomic_load(&grpA[lane & 15], __ATOMIC_RELAXED,
                                                __HIP_MEMORY_SCOPE_AGENT);
                unsigned v2 = __hip_atomic_load(&grpB[lane & 31], __ATOMIC_RELAXED,
                                                __HIP_MEMORY_SCOPE_AGENT);
                if (__ballot(v1 < t) == 0ull && __ballot(v2 < (t - 1)) == 0ull) break;
            }
            __syncthreads();
            {   // stage h0[t] and h1[t-1] (16 rows each)
                const int q = tid & 255;
                const float4* src = (tid < 256)
                    ? (const float4*)(h0_all + (size_t)t*BH + win)
                    : (const float4*)(h1_all + (size_t)(t-1)*BH + win);
                float4 rr[8];
#pragma unroll
                for (int i = 0; i < 8; ++i)
                    asm volatile("global_load_dwordx4 %0, %1, off sc0 sc1"
                                 : "=v"(rr[i]) : "v"(src + q + i*256));
                asm volatile("s_waitcnt vmcnt(0)" ::: "memory");
                __builtin_amdgcn_sched_barrier(0);
                float4* dst = (float4*)(xs + ((tid < 256) ? 0 : 8192));
#pragma unroll
                for (int i = 0; i < 8; ++i) dst[q + i*256] = rr[i];
            }
            __syncthreads();
#pragma unroll
            for (int i = 0; i < 64; ++i) a[i] = 0.f;
            const float* xsrc = xs + (kt ? 8192 : 0);
#pragma unroll
            for (int b = 0; b < 8; ++b) {
                const int row = (bt << 3) + b;
                float4 ha = *(const float4*)&xsrc[row*512 + lane*4];
                float4 hb = *(const float4*)&xsrc[row*512 + 256 + lane*4];
#pragma unroll
                for (int jj = 0; jj < 8; ++jj) {
                    a[b*8+jj] += ha.x*wr[jj][0].x + ha.y*wr[jj][0].y
                               + ha.z*wr[jj][0].z + ha.w*wr[jj][0].w
                               + hb.x*wr[jj][1].x + hb.y*wr[jj][1].y
                               + hb.z*wr[jj][1].z + hb.w*wr[jj][1].w;
                }
            }
            BFLY(1,32) BFLY(2,16) BFLY(4,8) BFLY(8,4) BFLY(16,2) BFLY(32,1)
            __syncthreads();
            if (kt) xs[scx] = a[0];            // scratch: reuse xs[0..255]
            __syncthreads();
            if (!kt) {
                float v = tanhf(a[0] + xs[scx] + bias);
                __hip_atomic_store(&h1_all[(size_t)t*BH + (size_t)bg*HID + jg], v,
                                   __ATOMIC_RELAXED, __HIP_MEMORY_SCOPE_AGENT);
            }
            asm volatile("s_waitcnt vmcnt(0)" ::: "memory");
            __syncthreads();
            if (tid == 0) __hip_atomic_store(myf, t, __ATOMIC_RELAXED,
                                             __HIP_MEMORY_SCOPE_AGENT);
        }
    }
}

__global__ __launch_bounds__(256) void copy_out_k(const float* __restrict__ h0_all,
                                                  const float* __restrict__ h1_all,
                                                  float* __restrict__ out_hidden) {
    int g = blockIdx.x * 256 + threadIdx.x;
    if (g < BH)            out_hidden[g] = h0_all[(size_t)SEQ * BH + g];
    else if (g < 2 * BH)   out_hidden[g] = h1_all[(size_t)SEQ * BH + (g - BH)];
}

// ---------------- bf16 split + 2-pass MFMA GEMM ----------------

__device__ __forceinline__ unsigned short bf16_rne(float x) {
    unsigned u = __float_as_uint(x);
    unsigned r = u + 0x7fffu + ((u >> 16) & 1u);
    return (unsigned short)(r >> 16);
}

// hi/lo split (lo nullable -> hi-only rounding)
__global__ __launch_bounds__(256) void split_bf16_k(const float* __restrict__ src,
                                                    unsigned short* __restrict__ hi,
                                                    unsigned short* __restrict__ lo,
                                                    int n4) {
    int i = blockIdx.x * 256 + threadIdx.x;
    if (i >= n4) return;
    float4 v = ((const float4*)src)[i];
    ushort4 h4;
    h4.x = bf16_rne(v.x); h4.y = bf16_rne(v.y);
    h4.z = bf16_rne(v.z); h4.w = bf16_rne(v.w);
    ((ushort4*)hi)[i] = h4;
    if (lo) {
        ushort4 l4;
        l4.x = bf16_rne(v.x - __uint_as_float((unsigned)h4.x << 16));
        l4.y = bf16_rne(v.y - __uint_as_float((unsigned)h4.y << 16));
        l4.z = bf16_rne(v.z - __uint_as_float((unsigned)h4.z << 16));
        l4.w = bf16_rne(v.w - __uint_as_float((unsigned)h4.w << 16));
        ((ushort4*)lo)[i] = l4;
    }
}

// C[M,N] = A[M,512] @ B[N,512]^T (+bias0+bias1); A as bf16 hi/lo pair (optional
// row gather via tok), B single-rounded bf16. acc = Ah*B + Al*B (2 MFMA passes).
// 128x128 tile, BK=64, XOR-swizzled LDS, mfma_f32_16x16x32_bf16.
__global__ __launch_bounds__(256) void gemm_mfma2_k(
    const unsigned short* __restrict__ Ahg, const unsigned short* __restrict__ Alg,
    const int* __restrict__ tok,
    const unsigned short* __restrict__ Bhg,
    const float* __restrict__ bias0, const float* __restrict__ bias1,
    float* __restrict__ C, int N, int ldc)
{
    __shared__ __align__(16) unsigned short sAh[128*64];
    __shared__ __align__(16) unsigned short sAl[128*64];
    __shared__ __align__(16) unsigned short sBh[128*64];

    const int tid = threadIdx.x;
    const int r0 = blockIdx.x * 128, c0 = blockIdx.y * 128;
    const int lane = tid & 63, wv = tid >> 6;
    const int mh = wv >> 1, nh = wv & 1;

    f32x4 acc[4][4];
#pragma unroll
    for (int i = 0; i < 4; ++i)
#pragma unroll
        for (int j = 0; j < 4; ++j) acc[i][j] = (f32x4){0.f, 0.f, 0.f, 0.f};

    const int srow = tid >> 1, shalf = tid & 1;
    const size_t arow = tok ? (size_t)tok[r0 + srow] : (size_t)(r0 + srow);
    const size_t abase = arow * 512 + shalf * 32;
    const int brow = c0 + srow;
    const bool bok = brow < N;
    const size_t bbase = (size_t)(bok ? brow : 0) * 512 + shalf * 32;
    const int woff = srow * 64;
    const int swz = srow & 7;

    for (int k0 = 0; k0 < 512; k0 += 64) {
        uint4 vah[4], val_[4], vbh[4];
#pragma unroll
        for (int g = 0; g < 4; ++g) {
            vah[g]  = *(const uint4*)(Ahg + abase + k0 + g*8);
            val_[g] = *(const uint4*)(Alg + abase + k0 + g*8);
            vbh[g] = bok ? *(const uint4*)(Bhg + bbase + k0 + g*8)
                         : (uint4){0,0,0,0};
        }
        __syncthreads();
#pragma unroll
        for (int g = 0; g < 4; ++g) {
            int off = woff + (((shalf*4 + g) ^ swz) * 8);
            *(uint4*)&sAh[off] = vah[g];
            *(uint4*)&sAl[off] = val_[g];
            *(uint4*)&sBh[off] = vbh[g];
        }
        __syncthreads();
#pragma unroll
        for (int c = 0; c < 2; ++c) {
            const int ks = ((c*4 + (lane >> 4)) ^ (lane & 7)) * 8;
            bf16x8 fAh[4], fAl[4], fBh[4];
#pragma unroll
            for (int mi = 0; mi < 4; ++mi) {
                int ro = (mh*64 + mi*16 + (lane & 15)) * 64;
                fAh[mi] = *(const bf16x8*)&sAh[ro + ks];
                fAl[mi] = *(const bf16x8*)&sAl[ro + ks];
            }
#pragma unroll
            for (int ni = 0; ni < 4; ++ni) {
                int ro = (nh*64 + ni*16 + (lane & 15)) * 64;
                fBh[ni] = *(const bf16x8*)&sBh[ro + ks];
            }
#pragma unroll
            for (int mi = 0; mi < 4; ++mi)
#pragma unroll
                for (int ni = 0; ni < 4; ++ni) {
                    acc[mi][ni] = __builtin_amdgcn_mfma_f32_16x16x32_bf16(
                        fAh[mi], fBh[ni], acc[mi][ni], 0, 0, 0);
                    acc[mi][ni] = __builtin_amdgcn_mfma_f32_16x16x32_bf16(
                        fAl[mi], fBh[ni], acc[mi][ni], 0, 0, 0);
                }
        }
        __syncthreads();
    }

#pragma unroll
    for (int ni = 0; ni < 4; ++ni) {
        int gcol = c0 + nh*64 + ni*16 + (lane & 15);
        bool ok = gcol < N;
        float bias = 0.f;
        if (ok) {
            if (bias0) bias += bias0[gcol];
            if (bias1) bias += bias1[gcol];
        }
#pragma unroll
        for (int mi = 0; mi < 4; ++mi) {
            int grow = r0 + mh*64 + mi*16 + ((lane >> 4) << 2);
#pragma unroll
            for (int r = 0; r < 4; ++r)
                if (ok) C[(size_t)(grow + r) * ldc + gcol] = acc[mi][ni][r] + bias;
        }
    }
}

extern "C" void kernel_launch(void* const* d_in, const int* in_sizes, int n_in,
                              void* d_out, int out_size, void* d_ws, size_t ws_size,
                              hipStream_t stream) {
    const int*   inputs = (const int*)d_in[0];
    const float* hidden = (const float*)d_in[1];
    const float* emb    = (const float*)d_in[2];
    const float* W_ih0  = (const float*)d_in[3];
    const float* b_ih0  = (const float*)d_in[4];
    const float* W_hh0  = (const float*)d_in[5];
    const float* b_hh0  = (const float*)d_in[6];
    const float* W_in   = (const float*)d_in[7];
    const float* b_in   = (const float*)d_in[8];
    const float* W_hh   = (const float*)d_in[9];
    const float* b_hh   = (const float*)d_in[10];
    const float* Wy     = (const float*)d_in[11];
    const float* by     = (const float*)d_in[12];
    float* out = (float*)d_out;

    float* ws     = (float*)d_ws;
    float* pre0   = ws + PRE0_OFF;
    float* h0_all = ws + H0_OFF;
    float* h1_all = ws + H1_OFF;
    unsigned* flags = (unsigned*)(ws + FLAGS_OFF);
    float* out_hidden = out + LOGITS_N;
    const bool big_ws = (ws_size >= WS_NEED_FLOATS * 4ull);

    // 1) initial hidden state -> slot 0; zero flags
    init_state_k<<<dim3((BH + 255) / 256), dim3(256), 0, stream>>>(hidden, h0_all, h1_all, flags);

    // 2) pre0 = emb[tok] @ W_ih0^T + b_ih0 + b_hh0   (M=8192, N=512, K=512)
    if (big_ws) {
        unsigned short* emb_hi  = (unsigned short*)(ws + CONV_OFF);
        unsigned short* emb_lo  = emb_hi + (size_t)VOC * EMBD;
        unsigned short* wih0_hi = emb_lo + (size_t)VOC * EMBD;
        split_bf16_k<<<dim3(5000), dim3(256), 0, stream>>>(emb, emb_hi, emb_lo, VOC*EMBD/4);
        split_bf16_k<<<dim3(1024), dim3(256), 0, stream>>>(W_ih0, wih0_hi, nullptr, HID*EMBD/4);
        gemm_mfma2_k<<<dim3(64, 4), dim3(256), 0, stream>>>(
            emb_hi, emb_lo, inputs, wih0_hi, b_ih0, b_hh0, pre0, HID, HID);
    } else {
        gemm_nt_k<<<dim3(64, 4), dim3(256), 0, stream>>>(
            emb, inputs, W_ih0, b_ih0, b_hh0, pre0, HID, EMBD, HID);
    }

    // 3) recurrence v4 (dataflow flags, W-in-VGPR, conflict-free LDS spans)
    const float* pre0_c = pre0;
    void* kargs[] = { (void*)&pre0_c, (void*)&W_hh0, (void*)&W_in, (void*)&b_in,
                      (void*)&W_hh, (void*)&b_hh, (void*)&h0_all, (void*)&h1_all,
                      (void*)&flags };
    hipLaunchCooperativeKernel((const void*)recurrence_k, dim3(192), dim3(512),
                               kargs, 0, stream);

    // 4) final hidden -> d_out tail
    copy_out_k<<<dim3(256), dim3(256), 0, stream>>>(h0_all, h1_all, out_hidden);

    // 5) logits = h1[1..128] @ Wy^T + by  (M=8192, N=10000, K=512)
    if (big_ws) {
        unsigned short* h_hi  = (unsigned short*)(ws + CONV_OFF);   // overlay on emb area
        unsigned short* h_lo  = h_hi + (size_t)8192 * 512;
        unsigned short* wy_hi = h_lo + (size_t)8192 * 512;
        split_bf16_k<<<dim3(4096), dim3(256), 0, stream>>>(h1_all + BH, h_hi, h_lo, 8192*512/4);
        split_bf16_k<<<dim3(5000), dim3(256), 0, stream>>>(Wy, wy_hi, nullptr, VOC*HID/4);
        gemm_mfma2_k<<<dim3(64, 79), dim3(256), 0, stream>>>(
            h_hi, h_lo, nullptr, wy_hi, by, nullptr, out, VOC, VOC);
    } else {
        gemm_nt_k<<<dim3(64, 79), dim3(256), 0, stream>>>(
            h1_all + BH, nullptr, Wy, nullptr, by, out, VOC, HID, VOC);
    }
}

// Round 9
// 1232.996 us; speedup vs baseline: 8.8626x; 1.1656x over previous
//
#include <hip/hip_runtime.h>
#include <hip/hip_bf16.h>

#define SEQ 128
#define BAT 64
#define VOC 10000
#define EMBD 512
#define HID 512
#define BH (BAT*HID)                  // 32768
// workspace layout (floats)
#define PRE0_OFF 0
#define H0_OFF   ((size_t)SEQ*BH)                 // pre0: 128*BH
#define H1_OFF   (H0_OFF + (size_t)(SEQ+1)*BH)
#define FLAGS_OFF (H1_OFF + (size_t)(SEQ+1)*BH)   // 256 uint flags
#define CONV_OFF (FLAGS_OFF + 256)                // bf16 weight arrays
#define LOGITS_N ((size_t)SEQ*BAT*VOC)            // 81,920,000 (in d_out)
// conv region (ushorts): wy_hi 5,120,000 + wih0_hi 262,144
#define CONV_USHORTS 5382144ull
#define WS_NEED_FLOATS (CONV_OFF + CONV_USHORTS/2)

typedef __attribute__((ext_vector_type(8))) __bf16 bf16x8;
typedef __attribute__((ext_vector_type(4))) float f32x4;

__global__ __launch_bounds__(256) void init_state_k(const float* __restrict__ hidden,
                                                    float* __restrict__ h0_0,
                                                    float* __restrict__ h1_0,
                                                    unsigned* __restrict__ flags) {
    int i = blockIdx.x * 256 + threadIdx.x;
    if (i < 256) flags[i] = 0u;
    if (i < BH) { h0_0[i] = hidden[i]; h1_0[i] = hidden[BH + i]; }
}

// fp32 GEMM fallback (only if ws too small for bf16-split path).
__global__ __launch_bounds__(256) void gemm_nt_k(
    const float* __restrict__ A, const int* __restrict__ tok,
    const float* __restrict__ Bm,
    const float* __restrict__ bias0, const float* __restrict__ bias1,
    float* __restrict__ C, int N, int K, int ldc)
{
    __shared__ float As[32][132];
    __shared__ float Bs[32][132];
    __shared__ int toks[128];

    const int tid = threadIdx.x;
    const int r0 = blockIdx.x * 128;
    const int c0 = blockIdx.y * 128;

    if (tok != nullptr && tid < 128) toks[tid] = tok[r0 + tid];
    __syncthreads();

    const int tn = tid & 15;
    const int tm = tid >> 4;
    const int m0 = tm * 8, n0 = tn * 8;

    float acc[8][8];
#pragma unroll
    for (int i = 0; i < 8; ++i)
#pragma unroll
        for (int j = 0; j < 8; ++j) acc[i][j] = 0.f;

    for (int k0 = 0; k0 < K; k0 += 32) {
#pragma unroll
        for (int p = 0; p < 4; ++p) {
            int idx = p * 256 + tid;
            int row = idx >> 3;
            int kq  = (idx & 7) << 2;
            size_t arow = tok ? (size_t)toks[row] : (size_t)(r0 + row);
            float4 a = *(const float4*)(A + arow * (size_t)K + k0 + kq);
            As[kq+0][row] = a.x; As[kq+1][row] = a.y;
            As[kq+2][row] = a.z; As[kq+3][row] = a.w;
            int gc = c0 + row;
            float4 b = make_float4(0.f, 0.f, 0.f, 0.f);
            if (gc < N) b = *(const float4*)(Bm + (size_t)gc * K + k0 + kq);
            Bs[kq+0][row] = b.x; Bs[kq+1][row] = b.y;
            Bs[kq+2][row] = b.z; Bs[kq+3][row] = b.w;
        }
        __syncthreads();
#pragma unroll 8
        for (int k = 0; k < 32; ++k) {
            float4 a0 = *(const float4*)&As[k][m0];
            float4 a1 = *(const float4*)&As[k][m0 + 4];
            float4 b0 = *(const float4*)&Bs[k][n0];
            float4 b1 = *(const float4*)&Bs[k][n0 + 4];
            float am[8] = {a0.x,a0.y,a0.z,a0.w,a1.x,a1.y,a1.z,a1.w};
            float bn[8] = {b0.x,b0.y,b0.z,b0.w,b1.x,b1.y,b1.z,b1.w};
#pragma unroll
            for (int i = 0; i < 8; ++i)
#pragma unroll
                for (int j = 0; j < 8; ++j) acc[i][j] += am[i] * bn[j];
        }
        __syncthreads();
    }

    const bool full = (c0 + 128 <= N);
#pragma unroll
    for (int i = 0; i < 8; ++i) {
        size_t r = (size_t)(r0 + m0 + i);
        float* crow = C + r * (size_t)ldc;
#pragma unroll
        for (int j = 0; j < 8; ++j) {
            int c = c0 + n0 + j;
            if (full || c < N) {
                float v = acc[i][j];
                if (bias0) v += bias0[c];
                if (bias1) v += bias1[c];
                crow[c] = v;
            }
        }
    }
}

// ---------------- recurrence v4 (round-6 passing version, verbatim) ----------
// 192 blocks x 512 threads (coop launch = co-residency only).
// blocks 0..63   (L1): groups g=blk/16 (16 batches), jb=blk%16 (32 j-rows).
// blocks 64..191 (L2): groups g=idx/32 (16 batches), jb=idx%32 (16 j-rows).
// Wave-tile 8b x 8j; lane owns k-span {4L..4L+3} U {256+4L..+3}. W resident in
// VGPRs all 128 steps. Butterfly all-reduce over 64 lanes.

#define BFLY(S, N)                                                     \
    {                                                                  \
        _Pragma("unroll")                                              \
        for (int i = 0; i < N; ++i) {                                  \
            float lo_ = a[i], hi_ = a[i + N];                          \
            float send_ = (lane & S) ? lo_ : hi_;                      \
            float recv_ = __shfl_xor(send_, S);                        \
            a[i] = ((lane & S) ? hi_ : lo_) + recv_;                   \
        }                                                              \
    }

__global__ __launch_bounds__(512) void recurrence_k(
    const float* __restrict__ pre0, const float* __restrict__ W_hh0,
    const float* __restrict__ W_in, const float* __restrict__ b_in,
    const float* __restrict__ W_hh, const float* __restrict__ b_hh,
    float* __restrict__ h0_all, float* __restrict__ h1_all,
    unsigned* __restrict__ flags)
{
    __shared__ float xs[16384];   // 64 KB: [h0 8192][h1 8192] (L1 uses first half)

    const int tid  = threadIdx.x;
    const int lane = tid & 63;
    const int wv   = tid >> 6;
    const int p = ((lane&1)<<5)|((lane&2)<<3)|((lane&4)<<1)
                | ((lane&8)>>1)|((lane&16)>>3)|((lane&32)>>5);  // bitrev6
    const int b_own = p >> 3, j_own = p & 7;

    unsigned* fl1 = flags;
    unsigned* fl2 = flags + 64;

    float4 wr[8][2];
    float a[64];

    if (blockIdx.x < 64) {                     // ---- layer 1 ----
        const int g = blockIdx.x >> 4, jb = blockIdx.x & 15;
        const int bt = wv & 1, jt = wv >> 1;
        const size_t win = (size_t)(g << 4) * HID;
#pragma unroll
        for (int jj = 0; jj < 8; ++jj) {
            const float* wp = W_hh0 + (size_t)(jb*32 + jt*8 + jj) * HID;
            wr[jj][0] = *(const float4*)(wp + lane*4);
            wr[jj][1] = *(const float4*)(wp + 256 + lane*4);
        }
        const unsigned* grp = fl1 + (g << 4);
        unsigned* myf = fl1 + (g << 4) + jb;
        const int bg = (g << 4) + (bt << 3) + b_own;
        const int jg = jb*32 + jt*8 + j_own;

        for (unsigned t = 1; t <= SEQ; ++t) {
            float pf = pre0[(size_t)(t-1)*BH + (size_t)bg*HID + jg];  // indep prefetch
            for (;;) {
                unsigned v = __hip_atomic_load(&grp[lane & 15], __ATOMIC_RELAXED,
                                               __HIP_MEMORY_SCOPE_AGENT);
                if (__ballot(v < (t - 1)) == 0ull) break;
            }
            __syncthreads();
            {   // stage h0[t-1][16 rows] -> xs (coherence-point bypass)
                const float4* src = (const float4*)(h0_all + (size_t)(t-1)*BH + win);
                float4 r0_, r1_, r2_, r3_;
                asm volatile("global_load_dwordx4 %0, %1, off sc0 sc1" : "=v"(r0_) : "v"(src + tid));
                asm volatile("global_load_dwordx4 %0, %1, off sc0 sc1" : "=v"(r1_) : "v"(src + tid + 512));
                asm volatile("global_load_dwordx4 %0, %1, off sc0 sc1" : "=v"(r2_) : "v"(src + tid + 1024));
                asm volatile("global_load_dwordx4 %0, %1, off sc0 sc1" : "=v"(r3_) : "v"(src + tid + 1536));
                asm volatile("s_waitcnt vmcnt(0)" ::: "memory");
                __builtin_amdgcn_sched_barrier(0);
                float4* dst = (float4*)xs;
                dst[tid] = r0_; dst[tid+512] = r1_; dst[tid+1024] = r2_; dst[tid+1536] = r3_;
            }
            __syncthreads();
#pragma unroll
            for (int i = 0; i < 64; ++i) a[i] = 0.f;
#pragma unroll
            for (int b = 0; b < 8; ++b) {
                const int row = (bt << 3) + b;
                float4 ha = *(const float4*)&xs[row*512 + lane*4];
                float4 hb = *(const float4*)&xs[row*512 + 256 + lane*4];
#pragma unroll
                for (int jj = 0; jj < 8; ++jj) {
                    a[b*8+jj] += ha.x*wr[jj][0].x + ha.y*wr[jj][0].y
                               + ha.z*wr[jj][0].z + ha.w*wr[jj][0].w
                               + hb.x*wr[jj][1].x + hb.y*wr[jj][1].y
                               + hb.z*wr[jj][1].z + hb.w*wr[jj][1].w;
                }
            }
            BFLY(1,32) BFLY(2,16) BFLY(4,8) BFLY(8,4) BFLY(16,2) BFLY(32,1)
            float v = tanhf(a[0] + pf);
            __hip_atomic_store(&h0_all[(size_t)t*BH + (size_t)bg*HID + jg], v,
                               __ATOMIC_RELAXED, __HIP_MEMORY_SCOPE_AGENT);
            asm volatile("s_waitcnt vmcnt(0)" ::: "memory");
            __syncthreads();
            if (tid == 0) __hip_atomic_store(myf, t, __ATOMIC_RELAXED,
                                             __HIP_MEMORY_SCOPE_AGENT);
        }
    } else {                                   // ---- layer 2 ----
        const int idx = blockIdx.x - 64;
        const int g = idx >> 5, jb = idx & 31;
        const int bt = wv & 1, jt = (wv >> 1) & 1, kt = wv >> 2;
        const size_t win = (size_t)(g << 4) * HID;
        const float* Wmat = kt ? W_hh : W_in;
#pragma unroll
        for (int jj = 0; jj < 8; ++jj) {
            const float* wp = Wmat + (size_t)(jb*16 + jt*8 + jj) * HID;
            wr[jj][0] = *(const float4*)(wp + lane*4);
            wr[jj][1] = *(const float4*)(wp + 256 + lane*4);
        }
        const unsigned* grpA = fl1 + (g << 4);
        const unsigned* grpB = fl2 + (g << 5);
        unsigned* myf = fl2 + (g << 5) + jb;
        const int bg = (g << 4) + (bt << 3) + b_own;
        const int jg = jb*16 + jt*8 + j_own;
        const float bias = b_in[jg] + b_hh[jg];
        const int scx = (wv & 3) * 64 + lane;

        for (unsigned t = 1; t <= SEQ; ++t) {
            for (;;) {
                unsigned v1 = __hip_atomic_load(&grpA[lane & 15], __ATOMIC_RELAXED,
                                                __HIP_MEMORY_SCOPE_AGENT);
                unsigned v2 = __hip_atomic_load(&grpB[lane & 31], __ATOMIC_RELAXED,
                                                __HIP_MEMORY_SCOPE_AGENT);
                if (__ballot(v1 < t) == 0ull && __ballot(v2 < (t - 1)) == 0ull) break;
            }
            __syncthreads();
            {   // stage h0[t] and h1[t-1] (16 rows each)
                const int q = tid & 255;
                const float4* src = (tid < 256)
                    ? (const float4*)(h0_all + (size_t)t*BH + win)
                    : (const float4*)(h1_all + (size_t)(t-1)*BH + win);
                float4 rr[8];
#pragma unroll
                for (int i = 0; i < 8; ++i)
                    asm volatile("global_load_dwordx4 %0, %1, off sc0 sc1"
                                 : "=v"(rr[i]) : "v"(src + q + i*256));
                asm volatile("s_waitcnt vmcnt(0)" ::: "memory");
                __builtin_amdgcn_sched_barrier(0);
                float4* dst = (float4*)(xs + ((tid < 256) ? 0 : 8192));
#pragma unroll
                for (int i = 0; i < 8; ++i) dst[q + i*256] = rr[i];
            }
            __syncthreads();
#pragma unroll
            for (int i = 0; i < 64; ++i) a[i] = 0.f;
            const float* xsrc = xs + (kt ? 8192 : 0);
#pragma unroll
            for (int b = 0; b < 8; ++b) {
                const int row = (bt << 3) + b;
                float4 ha = *(const float4*)&xsrc[row*512 + lane*4];
                float4 hb = *(const float4*)&xsrc[row*512 + 256 + lane*4];
#pragma unroll
                for (int jj = 0; jj < 8; ++jj) {
                    a[b*8+jj] += ha.x*wr[jj][0].x + ha.y*wr[jj][0].y
                               + ha.z*wr[jj][0].z + ha.w*wr[jj][0].w
                               + hb.x*wr[jj][1].x + hb.y*wr[jj][1].y
                               + hb.z*wr[jj][1].z + hb.w*wr[jj][1].w;
                }
            }
            BFLY(1,32) BFLY(2,16) BFLY(4,8) BFLY(8,4) BFLY(16,2) BFLY(32,1)
            __syncthreads();
            if (kt) xs[scx] = a[0];            // scratch: reuse xs[0..255]
            __syncthreads();
            if (!kt) {
                float v = tanhf(a[0] + xs[scx] + bias);
                __hip_atomic_store(&h1_all[(size_t)t*BH + (size_t)bg*HID + jg], v,
                                   __ATOMIC_RELAXED, __HIP_MEMORY_SCOPE_AGENT);
            }
            asm volatile("s_waitcnt vmcnt(0)" ::: "memory");
            __syncthreads();
            if (tid == 0) __hip_atomic_store(myf, t, __ATOMIC_RELAXED,
                                             __HIP_MEMORY_SCOPE_AGENT);
        }
    }
}

__global__ __launch_bounds__(256) void copy_out_k(const float* __restrict__ h0_all,
                                                  const float* __restrict__ h1_all,
                                                  float* __restrict__ out_hidden) {
    int g = blockIdx.x * 256 + threadIdx.x;
    if (g < BH)            out_hidden[g] = h0_all[(size_t)SEQ * BH + g];
    else if (g < 2 * BH)   out_hidden[g] = h1_all[(size_t)SEQ * BH + (g - BH)];
}

// ---------------- bf16 helpers + fused-split 2-pass MFMA GEMM ----------------

__device__ __forceinline__ unsigned bf16_rne(float x) {
    unsigned u = __float_as_uint(x);
    unsigned r = u + 0x7fffu + ((u >> 16) & 1u);
    return r >> 16;
}

// hi-only bf16 rounding of a weight matrix (B operand pre-split).
__global__ __launch_bounds__(256) void split_hi_k(const float* __restrict__ src,
                                                  unsigned short* __restrict__ hi,
                                                  int n4) {
    int i = blockIdx.x * 256 + threadIdx.x;
    if (i >= n4) return;
    float4 v = ((const float4*)src)[i];
    ushort4 h4;
    h4.x = (unsigned short)bf16_rne(v.x); h4.y = (unsigned short)bf16_rne(v.y);
    h4.z = (unsigned short)bf16_rne(v.z); h4.w = (unsigned short)bf16_rne(v.w);
    ((ushort4*)hi)[i] = h4;
}

// C[M,N] = A[M,512] @ B[N,512]^T (+bias0+bias1).
// A is fp32 (optional tok row-gather), split hi/lo bf16 IN-REGISTER during LDS
// staging (same global traffic as pre-split hi+lo: 4 B/elem). B pre-split bf16.
// acc = Ah*B + Al*B (2 MFMA passes). 128x128 tile, BK=64, XOR-swizzled LDS,
// 2-deep global->reg prefetch, bijective XCD blockIdx swizzle (grid%8==0).
__global__ __launch_bounds__(256) void gemm_mfma2f_k(
    const float* __restrict__ Ag, const int* __restrict__ tok,
    const unsigned short* __restrict__ Bhg,
    const float* __restrict__ bias0, const float* __restrict__ bias1,
    float* __restrict__ C, int N, int ldc)
{
    __shared__ __align__(16) unsigned short sAh[128*64];
    __shared__ __align__(16) unsigned short sAl[128*64];
    __shared__ __align__(16) unsigned short sBh[128*64];

    const int tid = threadIdx.x;
    const int flat = blockIdx.y * gridDim.x + blockIdx.x;
    const int cpx  = (gridDim.x * gridDim.y) >> 3;
    const int w    = (flat & 7) * cpx + (flat >> 3);
    const int r0 = (w & 63) * 128, c0 = (w >> 6) * 128;

    const int lane = tid & 63, wvv = tid >> 6;
    const int mh = wvv >> 1, nh = wvv & 1;

    f32x4 acc[4][4];
#pragma unroll
    for (int i = 0; i < 4; ++i)
#pragma unroll
        for (int j = 0; j < 4; ++j) acc[i][j] = (f32x4){0.f, 0.f, 0.f, 0.f};

    const int srow = tid >> 1, shalf = tid & 1;
    const size_t arow = tok ? (size_t)tok[r0 + srow] : (size_t)(r0 + srow);
    const size_t abase = arow * 512 + (size_t)shalf * 32;       // float index
    const int brow = c0 + srow;
    const bool bok = brow < N;
    const size_t bbase = (size_t)(bok ? brow : 0) * 512 + shalf * 32;  // ushort idx
    const int woff = srow * 64;
    const int swz = srow & 7;

    float4 fa[4][2];
    uint4 vbh[4];
#pragma unroll
    for (int g = 0; g < 4; ++g) {
        fa[g][0] = *(const float4*)(Ag + abase + g*8);
        fa[g][1] = *(const float4*)(Ag + abase + g*8 + 4);
        vbh[g]   = bok ? *(const uint4*)(Bhg + bbase + g*8) : (uint4){0,0,0,0};
    }

    for (int k0 = 0; k0 < 512; k0 += 64) {
        __syncthreads();
#pragma unroll
        for (int g = 0; g < 4; ++g) {
            float f[8] = {fa[g][0].x, fa[g][0].y, fa[g][0].z, fa[g][0].w,
                          fa[g][1].x, fa[g][1].y, fa[g][1].z, fa[g][1].w};
            unsigned hh[8], ll[8];
#pragma unroll
            for (int q = 0; q < 8; ++q) {
                hh[q] = bf16_rne(f[q]);
                ll[q] = bf16_rne(f[q] - __uint_as_float(hh[q] << 16));
            }
            uint4 ph = { hh[0] | (hh[1]<<16), hh[2] | (hh[3]<<16),
                         hh[4] | (hh[5]<<16), hh[6] | (hh[7]<<16) };
            uint4 pl = { ll[0] | (ll[1]<<16), ll[2] | (ll[3]<<16),
                         ll[4] | (ll[5]<<16), ll[6] | (ll[7]<<16) };
            int off = woff + (((shalf*4 + g) ^ swz) * 8);
            *(uint4*)&sAh[off] = ph;
            *(uint4*)&sAl[off] = pl;
            *(uint4*)&sBh[off] = vbh[g];
        }
        __syncthreads();
        if (k0 < 448) {
            const int kn = k0 + 64;
#pragma unroll
            for (int g = 0; g < 4; ++g) {
                fa[g][0] = *(const float4*)(Ag + abase + kn + g*8);
                fa[g][1] = *(const float4*)(Ag + abase + kn + g*8 + 4);
                vbh[g]   = bok ? *(const uint4*)(Bhg + bbase + kn + g*8) : (uint4){0,0,0,0};
            }
        }
#pragma unroll
        for (int c = 0; c < 2; ++c) {
            const int ks = ((c*4 + (lane >> 4)) ^ (lane & 7)) * 8;
            bf16x8 fAh[4], fAl[4], fBh[4];
#pragma unroll
            for (int mi = 0; mi < 4; ++mi) {
                int ro = (mh*64 + mi*16 + (lane & 15)) * 64;
                fAh[mi] = *(const bf16x8*)&sAh[ro + ks];
                fAl[mi] = *(const bf16x8*)&sAl[ro + ks];
            }
#pragma unroll
            for (int ni = 0; ni < 4; ++ni) {
                int ro = (nh*64 + ni*16 + (lane & 15)) * 64;
                fBh[ni] = *(const bf16x8*)&sBh[ro + ks];
            }
#pragma unroll
            for (int mi = 0; mi < 4; ++mi)
#pragma unroll
                for (int ni = 0; ni < 4; ++ni) {
                    acc[mi][ni] = __builtin_amdgcn_mfma_f32_16x16x32_bf16(
                        fAh[mi], fBh[ni], acc[mi][ni], 0, 0, 0);
                    acc[mi][ni] = __builtin_amdgcn_mfma_f32_16x16x32_bf16(
                        fAl[mi], fBh[ni], acc[mi][ni], 0, 0, 0);
                }
        }
    }

#pragma unroll
    for (int ni = 0; ni < 4; ++ni) {
        int gcol = c0 + nh*64 + ni*16 + (lane & 15);
        bool ok = gcol < N;
        float bias = 0.f;
        if (ok) {
            if (bias0) bias += bias0[gcol];
            if (bias1) bias += bias1[gcol];
        }
#pragma unroll
        for (int mi = 0; mi < 4; ++mi) {
            int grow = r0 + mh*64 + mi*16 + ((lane >> 4) << 2);
#pragma unroll
            for (int r = 0; r < 4; ++r)
                if (ok) C[(size_t)(grow + r) * ldc + gcol] = acc[mi][ni][r] + bias;
        }
    }
}

extern "C" void kernel_launch(void* const* d_in, const int* in_sizes, int n_in,
                              void* d_out, int out_size, void* d_ws, size_t ws_size,
                              hipStream_t stream) {
    const int*   inputs = (const int*)d_in[0];
    const float* hidden = (const float*)d_in[1];
    const float* emb    = (const float*)d_in[2];
    const float* W_ih0  = (const float*)d_in[3];
    const float* b_ih0  = (const float*)d_in[4];
    const float* W_hh0  = (const float*)d_in[5];
    const float* b_hh0  = (const float*)d_in[6];
    const float* W_in   = (const float*)d_in[7];
    const float* b_in   = (const float*)d_in[8];
    const float* W_hh   = (const float*)d_in[9];
    const float* b_hh   = (const float*)d_in[10];
    const float* Wy     = (const float*)d_in[11];
    const float* by     = (const float*)d_in[12];
    float* out = (float*)d_out;

    float* ws     = (float*)d_ws;
    float* pre0   = ws + PRE0_OFF;
    float* h0_all = ws + H0_OFF;
    float* h1_all = ws + H1_OFF;
    unsigned* flags = (unsigned*)(ws + FLAGS_OFF);
    float* out_hidden = out + LOGITS_N;
    const bool big_ws = (ws_size >= WS_NEED_FLOATS * 4ull);

    unsigned short* wy_hi   = (unsigned short*)(ws + CONV_OFF);
    unsigned short* wih0_hi = wy_hi + (size_t)VOC * HID;

    // 1) initial hidden state -> slot 0; zero flags
    init_state_k<<<dim3((BH + 255) / 256), dim3(256), 0, stream>>>(hidden, h0_all, h1_all, flags);

    // 2) pre0 = emb[tok] @ W_ih0^T + b_ih0 + b_hh0   (M=8192, N=512, K=512)
    if (big_ws) {
        split_hi_k<<<dim3(1024), dim3(256), 0, stream>>>(W_ih0, wih0_hi, HID*EMBD/4);
        split_hi_k<<<dim3(5000), dim3(256), 0, stream>>>(Wy, wy_hi, VOC*HID/4);
        gemm_mfma2f_k<<<dim3(64, 4), dim3(256), 0, stream>>>(
            emb, inputs, wih0_hi, b_ih0, b_hh0, pre0, HID, HID);
    } else {
        gemm_nt_k<<<dim3(64, 4), dim3(256), 0, stream>>>(
            emb, inputs, W_ih0, b_ih0, b_hh0, pre0, HID, EMBD, HID);
    }

    // 3) recurrence v4 (proven; dataflow flags, W-in-VGPR, block staging)
    const float* pre0_c = pre0;
    void* kargs[] = { (void*)&pre0_c, (void*)&W_hh0, (void*)&W_in, (void*)&b_in,
                      (void*)&W_hh, (void*)&b_hh, (void*)&h0_all, (void*)&h1_all,
                      (void*)&flags };
    hipLaunchCooperativeKernel((const void*)recurrence_k, dim3(192), dim3(512),
                               kargs, 0, stream);

    // 4) final hidden -> d_out tail
    copy_out_k<<<dim3(256), dim3(256), 0, stream>>>(h0_all, h1_all, out_hidden);

    // 5) logits = h1[1..128] @ Wy^T + by  (M=8192, N=10000, K=512)
    if (big_ws) {
        gemm_mfma2f_k<<<dim3(64, 79), dim3(256), 0, stream>>>(
            h1_all + BH, nullptr, wy_hi, by, nullptr, out, VOC, VOC);
    } else {
        gemm_nt_k<<<dim3(64, 79), dim3(256), 0, stream>>>(
            h1_all + BH, nullptr, Wy, nullptr, by, out, VOC, HID, VOC);
    }
}